// Round 2
// baseline (167295.715 us; speedup 1.0000x reference)
//
#include <hip/hip_runtime.h>
#include <math.h>

// ---- static dims ----
#define B8      8
#define LSEQ    512
#define NWG     256
#define TPB     512
#define RELK    97
#define BI      148

__device__ __forceinline__ float sigf(float x){
  return (x >= 0.f) ? 1.f/(1.f + expf(-x)) : expf(x)/(1.f + expf(x));
}
__device__ __forceinline__ float spf(float x){ // softplus, stable
  return (x > 0.f) ? x + log1pf(expf(-x)) : log1pf(expf(x));
}

// ---------------------------------------------------------------- sent gather
__global__ __launch_bounds__(256)
void k_sent(const int* __restrict__ cidx, const int* __restrict__ pos,
            const int* __restrict__ ner, const float* __restrict__ wemb,
            const float* __restrict__ eemb, const float* __restrict__ nemb,
            float* __restrict__ sent)
{
  int flat = blockIdx.x*256 + threadIdx.x;
  if (flat >= B8*LSEQ*140) return;
  int d = flat % 140; int bl = flat / 140;
  float v;
  if (d < 100)      v = wemb[(size_t)cidx[bl]*100 + d];
  else if (d < 120) v = eemb[(size_t)pos[bl]*20 + (d-100)];
  else              v = nemb[(size_t)ner[bl]*20 + (d-120)];
  sent[flat] = v;
}

// ---------------------------------------------------------- global barrier
__device__ __forceinline__ void gbar(int* cnt, int* gen){
  __syncthreads();
  if (threadIdx.x == 0){
    __threadfence();
    int g = __hip_atomic_load(gen, __ATOMIC_RELAXED, __HIP_MEMORY_SCOPE_AGENT);
    int v = __hip_atomic_fetch_add(cnt, 1, __ATOMIC_ACQ_REL, __HIP_MEMORY_SCOPE_AGENT);
    if (v == NWG-1){
      __hip_atomic_store(cnt, 0, __ATOMIC_RELAXED, __HIP_MEMORY_SCOPE_AGENT);
      __hip_atomic_fetch_add(gen, 1, __ATOMIC_RELEASE, __HIP_MEMORY_SCOPE_AGENT);
    } else {
      while (__hip_atomic_load(gen, __ATOMIC_RELAXED, __HIP_MEMORY_SCOPE_AGENT) == g)
        __builtin_amdgcn_s_sleep(1);
    }
    __threadfence();
  }
  __syncthreads();
}

// ------------------------------------- per-sample DNC memory addressing phase
// LDS carve offsets (floats) inside the 5824-float shared block
__device__ void mem_phase(float* lds, const float* __restrict__ xi,
                          float* __restrict__ M, float* u_g, float* ww_g,
                          float* p_g, float* wr_g, float* L_g, float* rout)
{
  const int tid = threadIdx.x;
  float* mL  = lds;          // [32][32]
  float* mwr = lds+1024;     // [8][32]
  float* mwrn= lds+1280;
  float* mcr = lds+1536;
  float* mfw = lds+1792;
  float* mbw = lds+2048;
  float* PSI = lds+2304;
  float* UU  = lds+2336;
  float* US  = lds+2368;
  float* AA  = lds+2400;
  float* CW  = lds+2432;
  float* WWN = lds+2464;
  float* WWO = lds+2496;
  float* PP  = lds+2528;
  int*   mord= (int*)(lds+2560);   // 32 ints
  float* mh  = lds+2592;           // rb[0..7] sf[8..15] sb[16..23] fg[24..31]
  float* mpi = lds+2656;           // [8][3]
  float* msc = lds+2688;           // 64 scratch scalars
  float* mq1 = lds+2752;           // 512
  float* mq2 = lds+3264;           // 512
  float* mp1 = lds+3776;           // [2][512]
  float* mp2 = lds+4800;           // [2][512]

  // ---- interface scalars / state load ----
  if (tid < 8){
    mh[tid]    = 1.f + spf(xi[4096+tid]);     // read strengths
    mh[8+tid]  = 1.f + spf(xi[10283+tid]);    // sf
    mh[16+tid] = 1.f + spf(xi[10291+tid]);    // sb
    mh[24+tid] = sigf(xi[5641+tid]);          // free gates
    float e0=xi[5651+3*tid], e1=xi[5652+3*tid], e2=xi[5653+3*tid];
    float mx=fmaxf(e0,fmaxf(e1,e2));
    float x0=expf(e0-mx), x1=expf(e1-mx), x2=expf(e2-mx);
    float inv=1.f/(x0+x1+x2);
    mpi[tid*3]=x0*inv; mpi[tid*3+1]=x1*inv; mpi[tid*3+2]=x2*inv;
  }
  if (tid==0){ msc[0]=1.f+spf(xi[4616]); msc[1]=sigf(xi[5649]); msc[2]=sigf(xi[5650]); }
  if (tid<32){ UU[tid]=u_g[tid]; WWO[tid]=ww_g[tid]; PP[tid]=p_g[tid]; }
  if (tid<256) mwr[tid]=wr_g[tid];
  mL[tid]=L_g[tid]; mL[tid+512]=L_g[tid+512];
  { float wm = 0.1f+0.9f*sigf(xi[5675+tid]); mq1[tid]=xi[4104+tid]*wm; mq2[tid]=wm; }
  __syncthreads();

  // psi, usage
  if (tid<32){
    float psi=1.f;
    #pragma unroll
    for (int r=0;r<8;r++) psi *= (1.f - mh[24+r]*mwr[r*32+tid]);
    PSI[tid]=psi;
    float uo=UU[tid], wo=WWO[tid];
    UU[tid]=(uo+wo-uo*wo)*psi;
  }
  __syncthreads();
  // stable ascending argsort of u
  if (tid<32){
    float un=UU[tid]; int rank=0;
    for (int m=0;m<32;m++){ float um=UU[m]; rank += (um<un)||(um==un && m<tid); }
    mord[rank]=tid;
  }
  __syncthreads();
  if (tid<32) US[tid]=UU[mord[tid]];
  __syncthreads();
  if (tid==0){ float cp=1.f; for (int j=0;j<32;j++){ AA[mord[j]]=(1.f-US[j])*cp; cp*=US[j]; } }
  __syncthreads();

  // write content weighting cw (OLD M)
  { float q=mq1[tid]*mq1[tid];
    for (int o=32;o;o>>=1) q += __shfl_down(q,o,64);
    if ((tid&63)==0) msc[8+(tid>>6)]=q; }
  __syncthreads();
  if (tid==0){ float q=0.f; for (int i=0;i<8;i++) q+=msc[8+i]; msc[3]=sqrtf(q); }
  __syncthreads();
  { int n=tid>>4, wsub=tid&15;
    float d=0.f,q=0.f;
    for (int i=0;i<32;i++){ int w=wsub+16*i; float m=M[(size_t)n*512+w]; float t2=m*mq2[w]; d+=mq1[w]*t2; q+=t2*t2; }
    for (int o=8;o;o>>=1){ d+=__shfl_down(d,o,16); q+=__shfl_down(q,o,16); }
    if (wsub==0){ float cs=d/(msc[3]*sqrtf(q)+1e-6f); CW[n]=msc[0]*cs; } }
  __syncthreads();
  if (tid==0){ float mx=-1e30f; for(int n=0;n<32;n++) mx=fmaxf(mx,CW[n]); msc[4]=mx; }
  __syncthreads();
  if (tid<32) CW[tid]=expf(CW[tid]-msc[4]);
  __syncthreads();
  if (tid==0){ float sm=0.f; for(int n=0;n<32;n++) sm+=CW[n]; msc[5]=1.f/sm; }
  __syncthreads();
  if (tid<32) CW[tid]*=msc[5];
  __syncthreads();
  // write weights
  if (tid<32) WWN[tid]=msc[2]*(msc[1]*AA[tid]+(1.f-msc[1])*CW[tid]);
  __syncthreads();
  // M dealloc + erase/write (w index == tid)
  { float er=sigf(xi[4617+tid]); float wv=xi[5129+tid];
    for (int n=0;n<32;n++){ size_t idx=(size_t)n*512+tid; float m=M[idx];
      M[idx]=m*PSI[n]*(1.f-WWN[n]*er)+WWN[n]*wv; } }
  __syncthreads();
  // link matrix (OLD p), then precedence
  for (int ii=0;ii<2;ii++){ int f=tid+512*ii; int i=f>>5, j=f&31;
    float nl=(1.f-WWN[i]-WWN[j])*mL[f]+WWN[i]*PP[j];
    mL[f]=(i==j)?0.f:nl; }
  __syncthreads();
  if (tid==0){ float sw=0.f; for(int n=0;n<32;n++) sw+=WWN[n]; msc[6]=sw; }
  __syncthreads();
  if (tid<32) PP[tid]=(1.f-msc[6])*PP[tid]+WWN[tid];
  __syncthreads();
  // fw/bw sharpened (OLD wr)
  { int r=(tid>>5)&7, i=tid&31; bool isB=(tid>=256);
    float accv=0.f;
    if (!isB){ for (int j=0;j<32;j++) accv += mL[i*32+j]*mwr[r*32+j]; }
    else     { for (int j=0;j<32;j++) accv += mL[j*32+i]*mwr[r*32+j]; }
    float sp = isB? mh[16+r] : mh[8+r];
    float e = expf(sp*logf(accv+1e-6f));
    if (!isB) mfw[r*32+i]=e; else mbw[r*32+i]=e; }
  __syncthreads();
  if (tid<16){ int r=tid&7; float sm=0.f;
    if (tid<8){ for(int n=0;n<32;n++) sm+=mfw[r*32+n]; msc[16+r]=1.f/sm; }
    else      { for(int n=0;n<32;n++) sm+=mbw[r*32+n]; msc[24+r]=1.f/sm; } }
  __syncthreads();
  { int r=(tid>>5)&7, i=tid&31; bool isB=(tid>=256);
    if (!isB) mfw[r*32+i]*=msc[16+r]; else mbw[r*32+i]*=msc[24+r]; }
  __syncthreads();
  // read content weighting cr (NEW M), 2 heads at a time
  for (int hp=0; hp<4; hp++){
    for (int rp2=0;rp2<2;rp2++){
      int r=hp*2+rp2;
      float rm=0.1f+0.9f*sigf(xi[6187+r*512+tid]);
      mp1[rp2*512+tid]=xi[r*512+tid]*rm;
      mp2[rp2*512+tid]=rm;
    }
    __syncthreads();
    for (int rp2=0;rp2<2;rp2++){
      float q=mp1[rp2*512+tid]; q*=q;
      for (int o=32;o;o>>=1) q+=__shfl_down(q,o,64);
      if ((tid&63)==0) msc[8+(tid>>6)]=q;
      __syncthreads();
      if (tid==0){ float qq=0.f; for(int i=0;i<8;i++) qq+=msc[8+i]; msc[32+rp2]=sqrtf(qq); }
      __syncthreads();
    }
    { int rp2=tid>>8, rem=tid&255, n=rem>>3, wsub=rem&7;
      float d=0.f,q=0.f;
      for (int i=0;i<64;i++){ int w=wsub*64+i; float m=M[(size_t)n*512+w]; float t2=m*mp2[rp2*512+w];
        d+=mp1[rp2*512+w]*t2; q+=t2*t2; }
      for (int o=4;o;o>>=1){ d+=__shfl_down(d,o,8); q+=__shfl_down(q,o,8); }
      if (wsub==0){ int r=hp*2+rp2; float cs=d/(msc[32+rp2]*sqrtf(q)+1e-6f); mcr[r*32+n]=mh[r]*cs; } }
    __syncthreads();
  }
  if (tid<8){ int r=tid; float mx=-1e30f;
    for (int n=0;n<32;n++) mx=fmaxf(mx,mcr[r*32+n]);
    float sm=0.f;
    for (int n=0;n<32;n++){ float e=expf(mcr[r*32+n]-mx); mcr[r*32+n]=e; sm+=e; }
    float inv=1.f/sm;
    for (int n=0;n<32;n++) mcr[r*32+n]*=inv; }
  __syncthreads();
  // new read weights
  if (tid<256){ int r=tid>>5, n=tid&31;
    float v=mpi[r*3]*mbw[r*32+n]+mpi[r*3+1]*mcr[r*32+n]+mpi[r*3+2]*mfw[r*32+n];
    mwrn[tid]=v; wr_g[tid]=v; }
  __syncthreads();
  // reads = wr_new @ M_new
  { int r=tid>>6, wsub=tid&63;
    for (int i2=0;i2<8;i2++){ int w=wsub+64*i2;
      float accv=0.f;
      for (int n=0;n<32;n++) accv+=mwrn[r*32+n]*M[(size_t)n*512+w];
      rout[r*512+w]=accv; } }
  // state writeback
  if (tid<32){ u_g[tid]=UU[tid]; ww_g[tid]=WWN[tid]; p_g[tid]=PP[tid]; }
  L_g[tid]=mL[tid]; L_g[tid+512]=mL[tid+512];
}

// ---------------------------------------------- persistent whole-recurrence
__global__ __launch_bounds__(TPB, 2)
void dnc_persist(
  const float* __restrict__ sent,
  const float* __restrict__ Wih0, const float* __restrict__ Whh0, const float* __restrict__ b0,
  const float* __restrict__ Wih1, const float* __restrict__ Whh1, const float* __restrict__ b1,
  const float* __restrict__ Wih2, const float* __restrict__ Whh2, const float* __restrict__ b2,
  const float* __restrict__ Wxi, const float* __restrict__ bxi,
  const float* __restrict__ Wout, const float* __restrict__ bout,
  float* __restrict__ Hh, float* __restrict__ yh,
  float* __restrict__ reads2,
  float* __restrict__ h0g, float* __restrict__ h1g, float* __restrict__ h2g,
  float* __restrict__ c0g, float* __restrict__ c1g, float* __restrict__ c2g,
  float* __restrict__ z0g, float* __restrict__ z1g, float* __restrict__ z2g,
  float* __restrict__ xig,
  float* __restrict__ Mb, float* __restrict__ ug, float* __restrict__ wwg,
  float* __restrict__ pg, float* __restrict__ wrg, float* __restrict__ Lg,
  int* bar)
{
  __shared__ float lds[5824];        // sA[8][520] + sRed[64]; mem carve overlaps
  float* sA   = lds;                 // row stride 520 floats (16B-aligned rows)
  float* sRed = lds + 4160;          // 64 floats
  const int wg  = blockIdx.x;
  const int tid = threadIdx.x;
  const int cq = tid >> 7, kq = tid & 127;   // z-gemm thread layout (4 cols/wg)
  const int xc = tid >> 6, xk = tid & 63;    // xi layout (48 cols/wg)
  int* cnt = bar; int* gen = bar+1;

  // ---------------- one-time: weight registers ----------------
  const int zcol = wg*4 + cq;
  float w0r[36];
  #pragma unroll
  for (int c=0;c<9;c++)
    #pragma unroll
    for (int i=0;i<4;i++){
      int k = c*512 + kq*4 + i;
      float v;
      if (k < 4236)      v = Wih0[(size_t)k*1024 + zcol];
      else if (k < 4492) v = Whh0[(size_t)(k-4236)*1024 + zcol];
      else               v = 0.f;
      w0r[c*4+i]=v;
    }
  float w1r[4], w2r[4];
  #pragma unroll
  for (int i=0;i<4;i++){
    int k = kq*4+i;
    w1r[i] = (k<256)? Wih1[(size_t)k*1024+zcol] : Whh1[(size_t)(k-256)*1024+zcol];
    w2r[i] = (k<256)? Wih2[(size_t)k*1024+zcol] : Whh2[(size_t)(k-256)*1024+zcol];
  }
  float wxr[24];
  #pragma unroll
  for (int cc=0;cc<6;cc++){
    int col = wg*48 + xc*6 + cc;
    #pragma unroll
    for (int i=0;i<4;i++){
      int k = xk*4+i;
      wxr[cc*4+i] = (col<10299)? Wxi[(size_t)k*10299 + col] : 0.f;
    }
  }
  float wyr[9];
  {
    bool isy = (wg>=8 && wg<148);
    int ycol = wg-8;
    #pragma unroll
    for (int c=0;c<9;c++){
      int k = c*512 + tid;
      wyr[c] = (isy && k<4352)? Wout[(size_t)k*140 + ycol] : 0.f;
    }
  }

  #pragma unroll 1
  for (int t=0; t<LSEQ; t++){
    const int rp = t&1, wp = rp^1;
    const float* readsPrev = reads2 + (size_t)((t-1)&1)*32768;

    // ================= phase A: z0 gemm (K=4492 padded to 4608) =========
    {
      float acc[8] = {0,0,0,0,0,0,0,0};
      const float* h0p = h0g + ((t-1)&1)*2048;
      float av[8];
      #pragma unroll
      for (int s=0;s<8;s++){
        int kg = tid;
        float v;
        if (kg < 140) v = sent[((size_t)s*512 + t)*140 + kg];
        else          v = readsPrev[s*4096 + kg - 140];
        av[s]=v;
      }
      for (int ch=0; ch<9; ch++){
        __syncthreads();
        #pragma unroll
        for (int s=0;s<8;s++) sA[s*520 + tid] = av[s];
        __syncthreads();
        if (ch < 8){
          int kg = (ch+1)*512 + tid;
          #pragma unroll
          for (int s=0;s<8;s++){
            float v;
            if (kg < 140)       v = sent[((size_t)s*512 + t)*140 + kg];
            else if (kg < 4236) v = readsPrev[s*4096 + kg - 140];
            else if (kg < 4492) v = h0p[s*256 + (kg-4236)];
            else                v = 0.f;
            av[s]=v;
          }
        }
        #pragma unroll
        for (int s=0;s<8;s++){
          float4 a = *reinterpret_cast<const float4*>(&sA[s*520 + (kq<<2)]);
          acc[s] += a.x*w0r[ch*4] + a.y*w0r[ch*4+1] + a.z*w0r[ch*4+2] + a.w*w0r[ch*4+3];
        }
      }
      #pragma unroll
      for (int o=32;o;o>>=1)
        #pragma unroll
        for (int s=0;s<8;s++) acc[s]+=__shfl_down(acc[s],o,64);
      if ((tid&63)==0){ int wv=tid>>6;
        #pragma unroll
        for (int s=0;s<8;s++) sRed[wv*8+s]=acc[s]; }
      __syncthreads();
      if (tid<32){ int c=tid>>3, s=tid&7;
        z0g[s*1024 + wg*4 + c] = sRed[c*16+s] + sRed[c*16+8+s] + b0[wg*4+c]; }
    }
    gbar(cnt,gen);

    // ================= phase B: cell0 + z1 gemm =========================
    {
      if (tid<256){
        int j=tid;
        #pragma unroll
        for (int s=0;s<8;s++){
          float zi=z0g[s*1024+j], zf=z0g[s*1024+256+j], zg=z0g[s*1024+512+j], zo=z0g[s*1024+768+j];
          float cold=c0g[rp*2048+s*256+j];
          float cn=sigf(zf)*cold+sigf(zi)*tanhf(zg);
          float h=sigf(zo)*tanhf(cn);
          sA[s*520+j]=h;
          if (wg==8){ c0g[wp*2048+s*256+j]=cn; h0g[rp*2048+s*256+j]=h; }
        }
      } else {
        int j=tid-256;
        const float* h1p = h1g + ((t-1)&1)*2048;
        #pragma unroll
        for (int s=0;s<8;s++) sA[s*520+256+j]=h1p[s*256+j];
      }
      __syncthreads();
      float acc[8]={0,0,0,0,0,0,0,0};
      #pragma unroll
      for (int s=0;s<8;s++){
        float4 a=*reinterpret_cast<const float4*>(&sA[s*520+(kq<<2)]);
        acc[s]+=a.x*w1r[0]+a.y*w1r[1]+a.z*w1r[2]+a.w*w1r[3];
      }
      #pragma unroll
      for (int o=32;o;o>>=1)
        #pragma unroll
        for (int s=0;s<8;s++) acc[s]+=__shfl_down(acc[s],o,64);
      if ((tid&63)==0){ int wv=tid>>6;
        #pragma unroll
        for (int s=0;s<8;s++) sRed[wv*8+s]=acc[s]; }
      __syncthreads();
      if (tid<32){ int c=tid>>3, s=tid&7;
        z1g[s*1024 + wg*4 + c] = sRed[c*16+s] + sRed[c*16+8+s] + b1[wg*4+c]; }
    }
    gbar(cnt,gen);

    // ================= phase C: cell1 + z2 gemm =========================
    {
      if (tid<256){
        int j=tid;
        #pragma unroll
        for (int s=0;s<8;s++){
          float zi=z1g[s*1024+j], zf=z1g[s*1024+256+j], zg=z1g[s*1024+512+j], zo=z1g[s*1024+768+j];
          float cold=c1g[rp*2048+s*256+j];
          float cn=sigf(zf)*cold+sigf(zi)*tanhf(zg);
          float h=sigf(zo)*tanhf(cn);
          sA[s*520+j]=h;
          if (wg==8){ c1g[wp*2048+s*256+j]=cn; h1g[rp*2048+s*256+j]=h; }
        }
      } else {
        int j=tid-256;
        const float* h2p = h2g + ((t-1)&1)*2048;
        #pragma unroll
        for (int s=0;s<8;s++) sA[s*520+256+j]=h2p[s*256+j];
      }
      __syncthreads();
      float acc[8]={0,0,0,0,0,0,0,0};
      #pragma unroll
      for (int s=0;s<8;s++){
        float4 a=*reinterpret_cast<const float4*>(&sA[s*520+(kq<<2)]);
        acc[s]+=a.x*w2r[0]+a.y*w2r[1]+a.z*w2r[2]+a.w*w2r[3];
      }
      #pragma unroll
      for (int o=32;o;o>>=1)
        #pragma unroll
        for (int s=0;s<8;s++) acc[s]+=__shfl_down(acc[s],o,64);
      if ((tid&63)==0){ int wv=tid>>6;
        #pragma unroll
        for (int s=0;s<8;s++) sRed[wv*8+s]=acc[s]; }
      __syncthreads();
      if (tid<32){ int c=tid>>3, s=tid&7;
        z2g[s*1024 + wg*4 + c] = sRed[c*16+s] + sRed[c*16+8+s] + b2[wg*4+c]; }
    }
    gbar(cnt,gen);

    // ================= phase D: cell2 + xi gemm =========================
    {
      if (tid<256){
        int j=tid;
        #pragma unroll
        for (int s=0;s<8;s++){
          float zi=z2g[s*1024+j], zf=z2g[s*1024+256+j], zg=z2g[s*1024+512+j], zo=z2g[s*1024+768+j];
          float cold=c2g[rp*2048+s*256+j];
          float cn=sigf(zf)*cold+sigf(zi)*tanhf(zg);
          float h2=sigf(zo)*tanhf(cn);
          float hc=fminf(fmaxf(h2,-20.f),20.f);
          sA[s*520+j]=hc;
          if (wg==8){ c2g[wp*2048+s*256+j]=cn; h2g[rp*2048+s*256+j]=h2;
                      Hh[((size_t)t*8+s)*256+j]=hc; }
        }
      }
      __syncthreads();
      float accx[6][8];
      #pragma unroll
      for (int cc=0;cc<6;cc++)
        #pragma unroll
        for (int s=0;s<8;s++) accx[cc][s]=0.f;
      #pragma unroll
      for (int s=0;s<8;s++){
        float4 a = *reinterpret_cast<const float4*>(&sA[s*520 + (xk<<2)]);
        #pragma unroll
        for (int cc=0;cc<6;cc++)
          accx[cc][s] += a.x*wxr[cc*4] + a.y*wxr[cc*4+1] + a.z*wxr[cc*4+2] + a.w*wxr[cc*4+3];
      }
      #pragma unroll
      for (int o=32;o;o>>=1)
        #pragma unroll
        for (int cc=0;cc<6;cc++)
          #pragma unroll
          for (int s=0;s<8;s++) accx[cc][s]+=__shfl_down(accx[cc][s],o,64);
      if ((tid&63)==0){
        #pragma unroll
        for (int cc=0;cc<6;cc++){
          int col = wg*48 + xc*6 + cc;
          if (col < 10299){
            #pragma unroll
            for (int s=0;s<8;s++) xig[(size_t)s*10299+col]=accx[cc][s]+bxi[col];
          }
        }
      }
    }
    gbar(cnt,gen);

    // ================= phase E: memory update (wg<8) + y(t-1) ==========
    if (wg < 8){
      mem_phase(lds, xig + (size_t)wg*10299, Mb + (size_t)wg*16384,
                ug+wg*32, wwg+wg*32, pg+wg*32, wrg+wg*256, Lg+wg*1024,
                reads2 + (size_t)rp*32768 + wg*4096);
    } else if (wg < 148 && t > 0){
      int ty = t-1, col = wg-8;
      const float* rdp = reads2 + (size_t)(ty&1)*32768;
      float acy[8]={0,0,0,0,0,0,0,0};
      #pragma unroll
      for (int ch=0;ch<9;ch++){
        int kg=ch*512+tid;
        #pragma unroll
        for (int s=0;s<8;s++){
          float a;
          if (kg<256)       a=Hh[((size_t)ty*8+s)*256+kg];
          else if (kg<4352) a=rdp[s*4096+kg-256];
          else              a=0.f;
          acy[s]+=a*wyr[ch];
        }
      }
      #pragma unroll
      for (int o=32;o;o>>=1)
        #pragma unroll
        for (int s=0;s<8;s++) acy[s]+=__shfl_down(acy[s],o,64);
      if ((tid&63)==0){ int wv=tid>>6;
        #pragma unroll
        for (int s=0;s<8;s++) sRed[wv*8+s]=acy[s]; }
      __syncthreads();
      if (tid<8){ float v=0.f;
        #pragma unroll
        for (int w=0;w<8;w++) v+=sRed[w*8+tid];
        yh[((size_t)tid*512+ty)*140+col]=v+bout[col]; }
    }
    gbar(cnt,gen);
  }

  // ---------------- final y(511) ----------------
  if (wg>=8 && wg<148){
    int ty = 511, col = wg-8;
    const float* rdp = reads2 + (size_t)(ty&1)*32768;
    float acy[8]={0,0,0,0,0,0,0,0};
    #pragma unroll
    for (int ch=0;ch<9;ch++){
      int kg=ch*512+tid;
      #pragma unroll
      for (int s=0;s<8;s++){
        float a;
        if (kg<256)       a=Hh[((size_t)ty*8+s)*256+kg];
        else if (kg<4352) a=rdp[s*4096+kg-256];
        else              a=0.f;
        acy[s]+=a*wyr[ch];
      }
    }
    #pragma unroll
    for (int o=32;o;o>>=1)
      #pragma unroll
      for (int s=0;s<8;s++) acy[s]+=__shfl_down(acy[s],o,64);
    if ((tid&63)==0){ int wv=tid>>6;
      #pragma unroll
      for (int s=0;s<8;s++) sRed[wv*8+s]=acy[s]; }
    __syncthreads();
    if (tid<8){ float v=0.f;
      #pragma unroll
      for (int w=0;w<8;w++) v+=sRed[w*8+tid];
      yh[((size_t)tid*512+ty)*140+col]=v+bout[col]; }
  }
}

// ---------------------------------------- generic 16-row tiled gemm (lda==K)
__global__ __launch_bounds__(256)
void gemm16(int M, int N, int K,
            const float* __restrict__ A, long long sAb, int lda,
            const float* __restrict__ Bm, long long sBb, int ldb,
            float* __restrict__ C, long long sCb, int ldc,
            const float* __restrict__ bias, int relu)
{
  __shared__ float sAh[16*512];
  const int tid = threadIdx.x;
  const float* Ab = A + (size_t)blockIdx.y*sAb;
  const float* Bb = Bm + (size_t)blockIdx.y*sBb;
  float* Cb = C + (size_t)blockIdx.y*sCb;
  const int m0 = blockIdx.x*16;
  const int tot = 16*K;
  for (int f = tid; f < tot; f += 256) sAh[f] = Ab[(size_t)m0*lda + f]; // lda==K
  __syncthreads();
  int c = (tid & 63)*4; int rg = tid >> 6;
  if (c >= N) return;
  float acc[4][4] = {};
  for (int k=0;k<K;k++){
    float4 bv = *reinterpret_cast<const float4*>(Bb + (size_t)k*ldb + c);
    #pragma unroll
    for (int rr=0;rr<4;rr++){
      float a = sAh[(rg*4+rr)*K + k];
      acc[rr][0] += a*bv.x; acc[rr][1] += a*bv.y; acc[rr][2] += a*bv.z; acc[rr][3] += a*bv.w;
    }
  }
  for (int rr=0;rr<4;rr++){
    int m = m0 + rg*4 + rr;
    #pragma unroll
    for (int e=0;e<4;e++){
      float v = acc[rr][e] + (bias ? bias[c+e] : 0.f);
      if (relu) v = fmaxf(v, 0.f);
      Cb[(size_t)m*ldc + c + e] = v;
    }
  }
}

// ------------------------------------------------------------ bilinear head
__global__ __launch_bounds__(256)
void bilin(const float* __restrict__ s0, const float* __restrict__ t0,
           const float* __restrict__ dis_emb, const int* __restrict__ dht,
           const int* __restrict__ dth, const float* __restrict__ Wb,
           const float* __restrict__ bb, float* __restrict__ out)
{
  __shared__ float sS[BI][33];
  __shared__ float sT[32][152];
  const int tid = threadIdx.x;
  const int bp0 = blockIdx.x*32;
  for (int f = tid; f < 32*BI; f += 256){
    int pp = f / BI, i = f % BI;
    int bp = bp0 + pp;
    float sv, tv;
    if (i < 128){ sv = s0[(size_t)bp*128 + i]; tv = t0[(size_t)bp*128 + i]; }
    else {
      sv = dis_emb[(size_t)dht[bp]*20 + (i-128)];
      tv = dis_emb[(size_t)dth[bp]*20 + (i-128)];
    }
    sS[i][pp] = sv; sT[pp][i] = tv;
  }
  __syncthreads();
  const int ppg = tid >> 5, jb = tid & 31;
  const int pp0 = ppg*4;
  const int k0 = blockIdx.y*49, kend = min(k0+49, RELK);
  for (int k = k0; k < kend; k++){
    const float* Wk = Wb + (size_t)k*BI*BI;
    float acc[4][5];
    #pragma unroll
    for (int a=0;a<4;a++) for (int b=0;b<5;b++) acc[a][b]=0.f;
    for (int i=0;i<BI;i++){
      float sv0 = sS[i][pp0], sv1 = sS[i][pp0+1], sv2 = sS[i][pp0+2], sv3 = sS[i][pp0+3];
      const float* wrow = Wk + i*BI;
      #pragma unroll
      for (int jj=0;jj<5;jj++){
        int j = jb + 32*jj;
        if (j < BI){
          float w = wrow[j];
          acc[0][jj] += sv0*w; acc[1][jj] += sv1*w; acc[2][jj] += sv2*w; acc[3][jj] += sv3*w;
        }
      }
    }
    float dot[4] = {0.f,0.f,0.f,0.f};
    #pragma unroll
    for (int jj=0;jj<5;jj++){
      int j = jb + 32*jj;
      if (j < BI){
        #pragma unroll
        for (int p4=0;p4<4;p4++) dot[p4] += acc[p4][jj]*sT[pp0+p4][j];
      }
    }
    #pragma unroll
    for (int p4=0;p4<4;p4++)
      for (int o=16;o;o>>=1) dot[p4] += __shfl_down(dot[p4], o, 32);
    if (jb == 0){
      #pragma unroll
      for (int p4=0;p4<4;p4++)
        out[(size_t)(bp0+pp0+p4)*RELK + k] = dot[p4] + bb[k];
    }
  }
}

// =========================================================== host launcher
extern "C" void kernel_launch(void* const* d_in, const int* in_sizes, int n_in,
                              void* d_out, int out_size, void* d_ws, size_t ws_size,
                              hipStream_t stream)
{
  (void)in_sizes; (void)n_in; (void)out_size; (void)ws_size;
  const int*   ctx_idx = (const int*)  d_in[0];
  const int*   pos     = (const int*)  d_in[1];
  const int*   nerI    = (const int*)  d_in[2];
  const float* h_map   = (const float*)d_in[5];
  const float* t_map   = (const float*)d_in[6];
  const int*   dht     = (const int*)  d_in[8];
  const int*   dth     = (const int*)  d_in[9];
  const float* wemb    = (const float*)d_in[10];
  const float* eemb    = (const float*)d_in[11];
  const float* nemb    = (const float*)d_in[12];
  const float* demb    = (const float*)d_in[13];
  const float* Wih0    = (const float*)d_in[14];
  const float* Whh0    = (const float*)d_in[15];
  const float* b0      = (const float*)d_in[16];
  const float* Wih1    = (const float*)d_in[17];
  const float* Whh1    = (const float*)d_in[18];
  const float* b1      = (const float*)d_in[19];
  const float* Wih2    = (const float*)d_in[20];
  const float* Whh2    = (const float*)d_in[21];
  const float* b2      = (const float*)d_in[22];
  const float* Wxi     = (const float*)d_in[23];
  const float* bxi     = (const float*)d_in[24];
  const float* Wout    = (const float*)d_in[25];
  const float* bout    = (const float*)d_in[26];
  const float* Wfin    = (const float*)d_in[27];
  const float* bfin    = (const float*)d_in[28];
  const float* Wre     = (const float*)d_in[29];
  const float* bre     = (const float*)d_in[30];
  const float* Wbili   = (const float*)d_in[31];
  const float* bbili   = (const float*)d_in[32];

  float* ws    = (float*)d_ws;
  float* sent  = ws;                    // [8][512][140]   573440
  float* Hh    = sent + 573440;         // [512][8][256]  1048576
  float* yh    = Hh + 1048576;          // [8][512][140]   573440
  float* s0b   = yh + 573440;           // [4096][128]     524288
  float* t0b   = s0b + 524288;          // [4096][128]     524288
  float* reads2= t0b + 524288;          // [2][8][4096]     65536
  float* h0g   = reads2 + 65536;        // [2][8][256]       4096
  float* h1g   = h0g + 4096;
  float* h2g   = h1g + 4096;
  float* c0g   = h2g + 4096;
  float* c1g   = c0g + 4096;
  float* c2g   = c1g + 4096;
  float* z0g   = c2g + 4096;            // [8][1024]         8192
  float* z1g   = z0g + 8192;
  float* z2g   = z1g + 8192;
  float* xig   = z2g + 8192;            // [8][10299]       82392
  float* Mb    = xig + 82392;           // [8][32][512]    131072
  float* ug    = Mb + 131072;           // [8][32]
  float* wwg   = ug + 256;
  float* pg    = wwg + 256;
  float* wrg   = pg + 256;              // [8][8][32]
  float* Lg    = wrg + 2048;            // [8][32][32]
  float* barf  = Lg + 8192;             // barrier ints
  float* o256  = Hh;                    // alias: Hh dead after persist
  float* ctxb  = sent;                  // alias: sent dead after persist

  size_t stateFloats = (size_t)((barf + 16) - reads2);
  hipMemsetAsync(reads2, 0, stateFloats*sizeof(float), stream);

  hipLaunchKernelGGL(k_sent, dim3((573440+255)/256), dim3(256), 0, stream,
                     ctx_idx, pos, nerI, wemb, eemb, nemb, sent);

  hipLaunchKernelGGL(dnc_persist, dim3(NWG), dim3(TPB), 0, stream,
                     sent, Wih0, Whh0, b0, Wih1, Whh1, b1, Wih2, Whh2, b2,
                     Wxi, bxi, Wout, bout, Hh, yh, reads2,
                     h0g, h1g, h2g, c0g, c1g, c2g, z0g, z1g, z2g, xig,
                     Mb, ug, wwg, pg, wrg, Lg, (int*)barf);

  // out = ys @ W_final + b_final          [4096,140]x[140,256]
  hipLaunchKernelGGL(gemm16, dim3(256,1), dim3(256), 0, stream,
                     4096, 256, 140, yh, (long long)0, 140, Wfin, (long long)0, 256,
                     o256, (long long)0, 256, bfin, 0);
  // ctx = relu(out @ W_re + b_re)         [4096,256]x[256,128]
  hipLaunchKernelGGL(gemm16, dim3(256,1), dim3(256), 0, stream,
                     4096, 128, 256, o256, (long long)0, 256, Wre, (long long)0, 128,
                     ctxb, (long long)0, 128, bre, 1);
  // s0 / t0 : per-batch [512,512]x[512,128]
  hipLaunchKernelGGL(gemm16, dim3(32,8), dim3(256), 0, stream,
                     512, 128, 512, h_map, (long long)(512*512), 512,
                     ctxb, (long long)(512*128), 128,
                     s0b, (long long)(512*128), 128, (const float*)nullptr, 0);
  hipLaunchKernelGGL(gemm16, dim3(32,8), dim3(256), 0, stream,
                     512, 128, 512, t_map, (long long)(512*512), 512,
                     ctxb, (long long)(512*128), 128,
                     t0b, (long long)(512*128), 128, (const float*)nullptr, 0);
  // bilinear head
  hipLaunchKernelGGL(bilin, dim3(128,2), dim3(256), 0, stream,
                     s0b, t0b, demb, dht, dth, Wbili, bbili, (float*)d_out);
}

// Round 3
// 114372.412 us; speedup vs baseline: 1.4627x; 1.4627x over previous
//
#include <hip/hip_runtime.h>
#include <math.h>

// ---- static dims ----
#define B8      8
#define LSEQ    512
#define NWG     256
#define TPB     512
#define RELK    97
#define BI      148
#define FSTR    16        // barrier flag stride (ints) = 64B

__device__ __forceinline__ float sigf(float x){
  return (x >= 0.f) ? 1.f/(1.f + expf(-x)) : expf(x)/(1.f + expf(x));
}
__device__ __forceinline__ float spf(float x){ // softplus, stable
  return (x > 0.f) ? x + log1pf(expf(-x)) : log1pf(expf(x));
}

// ---------------------------------------------------------------- sent gather
__global__ __launch_bounds__(256)
void k_sent(const int* __restrict__ cidx, const int* __restrict__ pos,
            const int* __restrict__ ner, const float* __restrict__ wemb,
            const float* __restrict__ eemb, const float* __restrict__ nemb,
            float* __restrict__ sent)
{
  int flat = blockIdx.x*256 + threadIdx.x;
  if (flat >= B8*LSEQ*140) return;
  int d = flat % 140; int bl = flat / 140;
  float v;
  if (d < 100)      v = wemb[(size_t)cidx[bl]*100 + d];
  else if (d < 120) v = eemb[(size_t)pos[bl]*20 + (d-100)];
  else              v = nemb[(size_t)ner[bl]*20 + (d-120)];
  sent[flat] = v;
}

// ------------------------------------------- weight transpose/concat (once)
// T[c*K2 + k] = k<K1a ? A[k*N+c] : (k<K1a+K1b ? Bsrc[(k-K1a)*N+c] : 0)
__global__ __launch_bounds__(256)
void k_tr(const float* __restrict__ A, const float* __restrict__ Bsrc,
          int N, int K1a, int K1b, int K2, long long total, float* __restrict__ T)
{
  long long i = (long long)blockIdx.x*256 + threadIdx.x;
  if (i >= total) return;
  int k = (int)(i % K2);
  long long c = i / K2;
  float v = 0.f;
  if (k < K1a)            v = A[(size_t)k*N + c];
  else if (k < K1a+K1b)   v = Bsrc[(size_t)(k-K1a)*N + c];
  T[i] = v;
}

// ---------------------------------------------------------- global barrier
// flag-based: parallel arrival flags (64B apart), wg0 gathers, gen broadcast.
__device__ __forceinline__ void gbar(int* flags, int* gen, int seq){
  __syncthreads();
  const int tid = threadIdx.x;
  if (tid == 0){
    __threadfence();
    __hip_atomic_store(&flags[blockIdx.x*FSTR], seq, __ATOMIC_RELAXED, __HIP_MEMORY_SCOPE_AGENT);
  }
  if (blockIdx.x == 0){
    if (tid < NWG){
      while (__hip_atomic_load(&flags[tid*FSTR], __ATOMIC_RELAXED, __HIP_MEMORY_SCOPE_AGENT) < seq)
        __builtin_amdgcn_s_sleep(1);
    }
    __syncthreads();
    if (tid == 0)
      __hip_atomic_store(gen, seq, __ATOMIC_RELAXED, __HIP_MEMORY_SCOPE_AGENT);
  } else if (tid == 0){
    while (__hip_atomic_load(gen, __ATOMIC_RELAXED, __HIP_MEMORY_SCOPE_AGENT) < seq)
      __builtin_amdgcn_s_sleep(1);
  }
  if (tid == 0) __threadfence();
  __syncthreads();
}

// ------------------------------------- per-sample DNC memory addressing phase
__device__ void mem_phase(float* lds, const float* __restrict__ xi,
                          float* __restrict__ M, float* u_g, float* ww_g,
                          float* p_g, float* wr_g, float* L_g, float* rout)
{
  const int tid = threadIdx.x;
  float* mL  = lds;          // [32][32]
  float* mwr = lds+1024;     // [8][32]
  float* mwrn= lds+1280;
  float* mcr = lds+1536;
  float* mfw = lds+1792;
  float* mbw = lds+2048;
  float* PSI = lds+2304;
  float* UU  = lds+2336;
  float* US  = lds+2368;
  float* AA  = lds+2400;
  float* CW  = lds+2432;
  float* WWN = lds+2464;
  float* WWO = lds+2496;
  float* PP  = lds+2528;
  int*   mord= (int*)(lds+2560);   // 32 ints
  float* mh  = lds+2592;           // rb[0..7] sf[8..15] sb[16..23] fg[24..31]
  float* mpi = lds+2656;           // [8][3]
  float* msc = lds+2688;           // 64 scratch scalars
  float* mq1 = lds+2752;           // 512
  float* mq2 = lds+3264;           // 512
  float* mp1 = lds+3776;           // [2][512]
  float* mp2 = lds+4800;           // [2][512]

  // ---- interface scalars / state load ----
  if (tid < 8){
    mh[tid]    = 1.f + spf(xi[4096+tid]);     // read strengths
    mh[8+tid]  = 1.f + spf(xi[10283+tid]);    // sf
    mh[16+tid] = 1.f + spf(xi[10291+tid]);    // sb
    mh[24+tid] = sigf(xi[5641+tid]);          // free gates
    float e0=xi[5651+3*tid], e1=xi[5652+3*tid], e2=xi[5653+3*tid];
    float mx=fmaxf(e0,fmaxf(e1,e2));
    float x0=expf(e0-mx), x1=expf(e1-mx), x2=expf(e2-mx);
    float inv=1.f/(x0+x1+x2);
    mpi[tid*3]=x0*inv; mpi[tid*3+1]=x1*inv; mpi[tid*3+2]=x2*inv;
  }
  if (tid==0){ msc[0]=1.f+spf(xi[4616]); msc[1]=sigf(xi[5649]); msc[2]=sigf(xi[5650]); }
  if (tid<32){ UU[tid]=u_g[tid]; WWO[tid]=ww_g[tid]; PP[tid]=p_g[tid]; }
  if (tid<256) mwr[tid]=wr_g[tid];
  mL[tid]=L_g[tid]; mL[tid+512]=L_g[tid+512];
  { float wm = 0.1f+0.9f*sigf(xi[5675+tid]); mq1[tid]=xi[4104+tid]*wm; mq2[tid]=wm; }
  __syncthreads();

  // psi, usage
  if (tid<32){
    float psi=1.f;
    #pragma unroll
    for (int r=0;r<8;r++) psi *= (1.f - mh[24+r]*mwr[r*32+tid]);
    PSI[tid]=psi;
    float uo=UU[tid], wo=WWO[tid];
    UU[tid]=(uo+wo-uo*wo)*psi;
  }
  __syncthreads();
  // stable ascending argsort of u
  if (tid<32){
    float un=UU[tid]; int rank=0;
    for (int m=0;m<32;m++){ float um=UU[m]; rank += (um<un)||(um==un && m<tid); }
    mord[rank]=tid;
  }
  __syncthreads();
  if (tid<32) US[tid]=UU[mord[tid]];
  __syncthreads();
  if (tid==0){ float cp=1.f; for (int j=0;j<32;j++){ AA[mord[j]]=(1.f-US[j])*cp; cp*=US[j]; } }
  __syncthreads();

  // write content weighting cw (OLD M)
  { float q=mq1[tid]*mq1[tid];
    for (int o=32;o;o>>=1) q += __shfl_down(q,o,64);
    if ((tid&63)==0) msc[8+(tid>>6)]=q; }
  __syncthreads();
  if (tid==0){ float q=0.f; for (int i=0;i<8;i++) q+=msc[8+i]; msc[3]=sqrtf(q); }
  __syncthreads();
  { int n=tid>>4, wsub=tid&15;
    float d=0.f,q=0.f;
    for (int i=0;i<32;i++){ int w=wsub+16*i; float m=M[(size_t)n*512+w]; float t2=m*mq2[w]; d+=mq1[w]*t2; q+=t2*t2; }
    for (int o=8;o;o>>=1){ d+=__shfl_down(d,o,16); q+=__shfl_down(q,o,16); }
    if (wsub==0){ float cs=d/(msc[3]*sqrtf(q)+1e-6f); CW[n]=msc[0]*cs; } }
  __syncthreads();
  if (tid==0){ float mx=-1e30f; for(int n=0;n<32;n++) mx=fmaxf(mx,CW[n]); msc[4]=mx; }
  __syncthreads();
  if (tid<32) CW[tid]=expf(CW[tid]-msc[4]);
  __syncthreads();
  if (tid==0){ float sm=0.f; for(int n=0;n<32;n++) sm+=CW[n]; msc[5]=1.f/sm; }
  __syncthreads();
  if (tid<32) CW[tid]*=msc[5];
  __syncthreads();
  // write weights
  if (tid<32) WWN[tid]=msc[2]*(msc[1]*AA[tid]+(1.f-msc[1])*CW[tid]);
  __syncthreads();
  // M dealloc + erase/write (w index == tid)
  { float er=sigf(xi[4617+tid]); float wv=xi[5129+tid];
    for (int n=0;n<32;n++){ size_t idx=(size_t)n*512+tid; float m=M[idx];
      M[idx]=m*PSI[n]*(1.f-WWN[n]*er)+WWN[n]*wv; } }
  __syncthreads();
  // link matrix (OLD p), then precedence
  for (int ii=0;ii<2;ii++){ int f=tid+512*ii; int i=f>>5, j=f&31;
    float nl=(1.f-WWN[i]-WWN[j])*mL[f]+WWN[i]*PP[j];
    mL[f]=(i==j)?0.f:nl; }
  __syncthreads();
  if (tid==0){ float sw=0.f; for(int n=0;n<32;n++) sw+=WWN[n]; msc[6]=sw; }
  __syncthreads();
  if (tid<32) PP[tid]=(1.f-msc[6])*PP[tid]+WWN[tid];
  __syncthreads();
  // fw/bw sharpened (OLD wr)
  { int r=(tid>>5)&7, i=tid&31; bool isB=(tid>=256);
    float accv=0.f;
    if (!isB){ for (int j=0;j<32;j++) accv += mL[i*32+j]*mwr[r*32+j]; }
    else     { for (int j=0;j<32;j++) accv += mL[j*32+i]*mwr[r*32+j]; }
    float sp = isB? mh[16+r] : mh[8+r];
    float e = expf(sp*logf(accv+1e-6f));
    if (!isB) mfw[r*32+i]=e; else mbw[r*32+i]=e; }
  __syncthreads();
  if (tid<16){ int r=tid&7; float sm=0.f;
    if (tid<8){ for(int n=0;n<32;n++) sm+=mfw[r*32+n]; msc[16+r]=1.f/sm; }
    else      { for(int n=0;n<32;n++) sm+=mbw[r*32+n]; msc[24+r]=1.f/sm; } }
  __syncthreads();
  { int r=(tid>>5)&7, i=tid&31; bool isB=(tid>=256);
    if (!isB) mfw[r*32+i]*=msc[16+r]; else mbw[r*32+i]*=msc[24+r]; }
  __syncthreads();
  // read content weighting cr (NEW M), 2 heads at a time
  for (int hp=0; hp<4; hp++){
    for (int rp2=0;rp2<2;rp2++){
      int r=hp*2+rp2;
      float rm=0.1f+0.9f*sigf(xi[6187+r*512+tid]);
      mp1[rp2*512+tid]=xi[r*512+tid]*rm;
      mp2[rp2*512+tid]=rm;
    }
    __syncthreads();
    for (int rp2=0;rp2<2;rp2++){
      float q=mp1[rp2*512+tid]; q*=q;
      for (int o=32;o;o>>=1) q+=__shfl_down(q,o,64);
      if ((tid&63)==0) msc[8+(tid>>6)]=q;
      __syncthreads();
      if (tid==0){ float qq=0.f; for(int i=0;i<8;i++) qq+=msc[8+i]; msc[32+rp2]=sqrtf(qq); }
      __syncthreads();
    }
    { int rp2=tid>>8, rem=tid&255, n=rem>>3, wsub=rem&7;
      float d=0.f,q=0.f;
      for (int i=0;i<64;i++){ int w=wsub*64+i; float m=M[(size_t)n*512+w]; float t2=m*mp2[rp2*512+w];
        d+=mp1[rp2*512+w]*t2; q+=t2*t2; }
      for (int o=4;o;o>>=1){ d+=__shfl_down(d,o,8); q+=__shfl_down(q,o,8); }
      if (wsub==0){ int r=hp*2+rp2; float cs=d/(msc[32+rp2]*sqrtf(q)+1e-6f); mcr[r*32+n]=mh[r]*cs; } }
    __syncthreads();
  }
  if (tid<8){ int r=tid; float mx=-1e30f;
    for (int n=0;n<32;n++) mx=fmaxf(mx,mcr[r*32+n]);
    float sm=0.f;
    for (int n=0;n<32;n++){ float e=expf(mcr[r*32+n]-mx); mcr[r*32+n]=e; sm+=e; }
    float inv=1.f/sm;
    for (int n=0;n<32;n++) mcr[r*32+n]*=inv; }
  __syncthreads();
  // new read weights
  if (tid<256){ int r=tid>>5, n=tid&31;
    float v=mpi[r*3]*mbw[r*32+n]+mpi[r*3+1]*mcr[r*32+n]+mpi[r*3+2]*mfw[r*32+n];
    mwrn[tid]=v; wr_g[tid]=v; }
  __syncthreads();
  // reads = wr_new @ M_new
  { int r=tid>>6, wsub=tid&63;
    for (int i2=0;i2<8;i2++){ int w=wsub+64*i2;
      float accv=0.f;
      for (int n=0;n<32;n++) accv+=mwrn[r*32+n]*M[(size_t)n*512+w];
      rout[r*512+w]=accv; } }
  // state writeback
  if (tid<32){ u_g[tid]=UU[tid]; ww_g[tid]=WWN[tid]; p_g[tid]=PP[tid]; }
  L_g[tid]=mL[tid]; L_g[tid+512]=mL[tid+512];
}

// ---------------------------------------------- persistent whole-recurrence
// Weights streamed each step from TRANSPOSED copies (L2/L3-resident, coalesced).
__global__ __launch_bounds__(TPB, 1)
void dnc_persist(
  const float* __restrict__ sent,
  const float* __restrict__ WA,  const float* __restrict__ b0,   // [1024][4608]
  const float* __restrict__ W1,  const float* __restrict__ b1,   // [1024][512]
  const float* __restrict__ W2,  const float* __restrict__ b2,   // [1024][512]
  const float* __restrict__ WXI, const float* __restrict__ bxi,  // [10299][256]
  const float* __restrict__ WY,  const float* __restrict__ bout, // [140][4352]
  float* __restrict__ Hh, float* __restrict__ yh,
  float* __restrict__ reads2,
  float* __restrict__ h0g, float* __restrict__ h1g, float* __restrict__ h2g,
  float* __restrict__ c0g, float* __restrict__ c1g, float* __restrict__ c2g,
  float* __restrict__ z0g, float* __restrict__ z1g, float* __restrict__ z2g,
  float* __restrict__ xig,
  float* __restrict__ Mb, float* __restrict__ ug, float* __restrict__ wwg,
  float* __restrict__ pg, float* __restrict__ wrg, float* __restrict__ Lg,
  int* flags, int* gen)
{
  __shared__ float lds[5824];        // sA[8][520] + sRed[64]; mem carve overlaps
  float* sA   = lds;                 // row stride 520 floats
  float* sRed = lds + 4160;          // 64 floats
  const int wg  = blockIdx.x;
  const int tid = threadIdx.x;
  const int cq = tid >> 7, kq = tid & 127;   // z-gemm layout (4 cols/wg)
  const int xc = tid >> 6, xk = tid & 63;    // xi layout (48 cols/wg)
  int seq = 0;

  const float* wcolA = WA + (size_t)(wg*4 + cq)*4608;
  const float* wcol1 = W1 + (size_t)(wg*4 + cq)*512;
  const float* wcol2 = W2 + (size_t)(wg*4 + cq)*512;
  const bool  isy   = (wg >= 8 && wg < 148);
  const float* wcolY = WY + (size_t)(isy ? (wg-8) : 0)*4352;

  #pragma unroll 1
  for (int t=0; t<LSEQ; t++){
    const int rp = t&1, wp = rp^1, pprev = (t+1)&1;
    const float* readsPrev = reads2 + (size_t)pprev*32768;

    // ================= phase A: z0 gemm (K=4492 padded to 4608) =========
    {
      float4 w4[9];
      #pragma unroll
      for (int ch=0;ch<9;ch++)
        w4[ch] = *reinterpret_cast<const float4*>(&wcolA[ch*512 + (kq<<2)]);
      const float* h0p = h0g + pprev*2048;
      float acc[8] = {0,0,0,0,0,0,0,0};
      float av[8];
      #pragma unroll
      for (int s=0;s<8;s++){
        int kg = tid;
        av[s] = (kg<140) ? sent[((size_t)s*512 + t)*140 + kg]
                         : readsPrev[s*4096 + kg - 140];
      }
      #pragma unroll
      for (int ch=0; ch<9; ch++){
        __syncthreads();
        #pragma unroll
        for (int s=0;s<8;s++) sA[s*520 + tid] = av[s];
        __syncthreads();
        if (ch < 8){
          int kg = (ch+1)*512 + tid;
          #pragma unroll
          for (int s=0;s<8;s++){
            float v;
            if (kg < 140)       v = sent[((size_t)s*512 + t)*140 + kg];
            else if (kg < 4236) v = readsPrev[s*4096 + kg - 140];
            else if (kg < 4492) v = h0p[s*256 + (kg-4236)];
            else                v = 0.f;
            av[s]=v;
          }
        }
        #pragma unroll
        for (int s=0;s<8;s++){
          float4 a = *reinterpret_cast<const float4*>(&sA[s*520 + (kq<<2)]);
          acc[s] += a.x*w4[ch].x + a.y*w4[ch].y + a.z*w4[ch].z + a.w*w4[ch].w;
        }
      }
      #pragma unroll
      for (int o=32;o;o>>=1)
        #pragma unroll
        for (int s=0;s<8;s++) acc[s]+=__shfl_down(acc[s],o,64);
      if ((tid&63)==0){ int wv=tid>>6;
        #pragma unroll
        for (int s=0;s<8;s++) sRed[wv*8+s]=acc[s]; }
      __syncthreads();
      if (tid<32){ int c=tid>>3, s=tid&7;
        z0g[s*1024 + wg*4 + c] = sRed[c*16+s] + sRed[c*16+8+s] + b0[wg*4+c]; }
    }
    gbar(flags,gen,++seq);

    // ================= phase B: cell0 + z1 gemm =========================
    {
      float4 w1v = *reinterpret_cast<const float4*>(&wcol1[kq<<2]);
      if (tid<256){
        int j=tid;
        #pragma unroll
        for (int s=0;s<8;s++){
          float zi=z0g[s*1024+j], zf=z0g[s*1024+256+j], zg=z0g[s*1024+512+j], zo=z0g[s*1024+768+j];
          float cold=c0g[rp*2048+s*256+j];
          float cn=sigf(zf)*cold+sigf(zi)*tanhf(zg);
          float h=sigf(zo)*tanhf(cn);
          sA[s*520+j]=h;
          if (wg==8){ c0g[wp*2048+s*256+j]=cn; h0g[rp*2048+s*256+j]=h; }
        }
      } else {
        int j=tid-256;
        const float* h1p = h1g + pprev*2048;
        #pragma unroll
        for (int s=0;s<8;s++) sA[s*520+256+j]=h1p[s*256+j];
      }
      __syncthreads();
      float acc[8]={0,0,0,0,0,0,0,0};
      #pragma unroll
      for (int s=0;s<8;s++){
        float4 a=*reinterpret_cast<const float4*>(&sA[s*520+(kq<<2)]);
        acc[s]+=a.x*w1v.x+a.y*w1v.y+a.z*w1v.z+a.w*w1v.w;
      }
      #pragma unroll
      for (int o=32;o;o>>=1)
        #pragma unroll
        for (int s=0;s<8;s++) acc[s]+=__shfl_down(acc[s],o,64);
      if ((tid&63)==0){ int wv=tid>>6;
        #pragma unroll
        for (int s=0;s<8;s++) sRed[wv*8+s]=acc[s]; }
      __syncthreads();
      if (tid<32){ int c=tid>>3, s=tid&7;
        z1g[s*1024 + wg*4 + c] = sRed[c*16+s] + sRed[c*16+8+s] + b1[wg*4+c]; }
    }
    gbar(flags,gen,++seq);

    // ================= phase C: cell1 + z2 gemm =========================
    {
      float4 w2v = *reinterpret_cast<const float4*>(&wcol2[kq<<2]);
      if (tid<256){
        int j=tid;
        #pragma unroll
        for (int s=0;s<8;s++){
          float zi=z1g[s*1024+j], zf=z1g[s*1024+256+j], zg=z1g[s*1024+512+j], zo=z1g[s*1024+768+j];
          float cold=c1g[rp*2048+s*256+j];
          float cn=sigf(zf)*cold+sigf(zi)*tanhf(zg);
          float h=sigf(zo)*tanhf(cn);
          sA[s*520+j]=h;
          if (wg==8){ c1g[wp*2048+s*256+j]=cn; h1g[rp*2048+s*256+j]=h; }
        }
      } else {
        int j=tid-256;
        const float* h2p = h2g + pprev*2048;
        #pragma unroll
        for (int s=0;s<8;s++) sA[s*520+256+j]=h2p[s*256+j];
      }
      __syncthreads();
      float acc[8]={0,0,0,0,0,0,0,0};
      #pragma unroll
      for (int s=0;s<8;s++){
        float4 a=*reinterpret_cast<const float4*>(&sA[s*520+(kq<<2)]);
        acc[s]+=a.x*w2v.x+a.y*w2v.y+a.z*w2v.z+a.w*w2v.w;
      }
      #pragma unroll
      for (int o=32;o;o>>=1)
        #pragma unroll
        for (int s=0;s<8;s++) acc[s]+=__shfl_down(acc[s],o,64);
      if ((tid&63)==0){ int wv=tid>>6;
        #pragma unroll
        for (int s=0;s<8;s++) sRed[wv*8+s]=acc[s]; }
      __syncthreads();
      if (tid<32){ int c=tid>>3, s=tid&7;
        z2g[s*1024 + wg*4 + c] = sRed[c*16+s] + sRed[c*16+8+s] + b2[wg*4+c]; }
    }
    gbar(flags,gen,++seq);

    // ================= phase D: cell2 + xi gemm =========================
    {
      float4 wx4[6];
      #pragma unroll
      for (int cc=0;cc<6;cc++){
        int col = wg*48 + xc*6 + cc;
        int colc = (col < 10299) ? col : 10298;
        wx4[cc] = *reinterpret_cast<const float4*>(&WXI[(size_t)colc*256 + (xk<<2)]);
      }
      if (tid<256){
        int j=tid;
        #pragma unroll
        for (int s=0;s<8;s++){
          float zi=z2g[s*1024+j], zf=z2g[s*1024+256+j], zg=z2g[s*1024+512+j], zo=z2g[s*1024+768+j];
          float cold=c2g[rp*2048+s*256+j];
          float cn=sigf(zf)*cold+sigf(zi)*tanhf(zg);
          float h2=sigf(zo)*tanhf(cn);
          float hc=fminf(fmaxf(h2,-20.f),20.f);
          sA[s*520+j]=hc;
          if (wg==8){ c2g[wp*2048+s*256+j]=cn; h2g[rp*2048+s*256+j]=h2;
                      Hh[((size_t)t*8+s)*256+j]=hc; }
        }
      }
      __syncthreads();
      float accx[6][8];
      #pragma unroll
      for (int cc=0;cc<6;cc++)
        #pragma unroll
        for (int s=0;s<8;s++) accx[cc][s]=0.f;
      #pragma unroll
      for (int s=0;s<8;s++){
        float4 a = *reinterpret_cast<const float4*>(&sA[s*520 + (xk<<2)]);
        #pragma unroll
        for (int cc=0;cc<6;cc++)
          accx[cc][s] += a.x*wx4[cc].x + a.y*wx4[cc].y + a.z*wx4[cc].z + a.w*wx4[cc].w;
      }
      #pragma unroll
      for (int o=32;o;o>>=1)
        #pragma unroll
        for (int cc=0;cc<6;cc++)
          #pragma unroll
          for (int s=0;s<8;s++) accx[cc][s]+=__shfl_down(accx[cc][s],o,64);
      if ((tid&63)==0){
        #pragma unroll
        for (int cc=0;cc<6;cc++){
          int col = wg*48 + xc*6 + cc;
          if (col < 10299){
            #pragma unroll
            for (int s=0;s<8;s++) xig[(size_t)s*10299+col]=accx[cc][s]+bxi[col];
          }
        }
      }
    }
    gbar(flags,gen,++seq);

    // ================= phase E: memory update (wg<8) + y(t-1) ==========
    if (wg < 8){
      mem_phase(lds, xig + (size_t)wg*10299, Mb + (size_t)wg*16384,
                ug+wg*32, wwg+wg*32, pg+wg*32, wrg+wg*256, Lg+wg*1024,
                reads2 + (size_t)rp*32768 + wg*4096);
    } else if (isy && t > 0){
      int ty = t-1;
      const float* rdp = reads2 + (size_t)(ty&1)*32768;
      float wy[9];
      #pragma unroll
      for (int ch=0;ch<9;ch++){ int k=ch*512+tid; wy[ch]=(k<4352)? wcolY[k] : 0.f; }
      float acy[8]={0,0,0,0,0,0,0,0};
      #pragma unroll
      for (int ch=0;ch<9;ch++){
        int kg=ch*512+tid;
        #pragma unroll
        for (int s=0;s<8;s++){
          float a;
          if (kg<256)       a=Hh[((size_t)ty*8+s)*256+kg];
          else if (kg<4352) a=rdp[s*4096+kg-256];
          else              a=0.f;
          acy[s]+=a*wy[ch];
        }
      }
      #pragma unroll
      for (int o=32;o;o>>=1)
        #pragma unroll
        for (int s=0;s<8;s++) acy[s]+=__shfl_down(acy[s],o,64);
      if ((tid&63)==0){ int wv=tid>>6;
        #pragma unroll
        for (int s=0;s<8;s++) sRed[wv*8+s]=acy[s]; }
      __syncthreads();
      if (tid<8){ float v=0.f;
        #pragma unroll
        for (int w=0;w<8;w++) v+=sRed[w*8+tid];
        yh[((size_t)tid*512+ty)*140+(wg-8)]=v+bout[wg-8]; }
    }
    gbar(flags,gen,++seq);
  }

  // ---------------- final y(511) ----------------
  if (isy){
    int ty = 511;
    const float* rdp = reads2 + (size_t)(ty&1)*32768;
    float wy[9];
    #pragma unroll
    for (int ch=0;ch<9;ch++){ int k=ch*512+tid; wy[ch]=(k<4352)? wcolY[k] : 0.f; }
    float acy[8]={0,0,0,0,0,0,0,0};
    #pragma unroll
    for (int ch=0;ch<9;ch++){
      int kg=ch*512+tid;
      #pragma unroll
      for (int s=0;s<8;s++){
        float a;
        if (kg<256)       a=Hh[((size_t)ty*8+s)*256+kg];
        else if (kg<4352) a=rdp[s*4096+kg-256];
        else              a=0.f;
        acy[s]+=a*wy[ch];
      }
    }
    #pragma unroll
    for (int o=32;o;o>>=1)
      #pragma unroll
      for (int s=0;s<8;s++) acy[s]+=__shfl_down(acy[s],o,64);
    if ((tid&63)==0){ int wv=tid>>6;
      #pragma unroll
      for (int s=0;s<8;s++) sRed[wv*8+s]=acy[s]; }
    __syncthreads();
    if (tid<8){ float v=0.f;
      #pragma unroll
      for (int w=0;w<8;w++) v+=sRed[w*8+tid];
      yh[((size_t)tid*512+ty)*140+(wg-8)]=v+bout[wg-8]; }
  }
}

// ---------------------------------------- generic 16-row tiled gemm (lda==K)
__global__ __launch_bounds__(256)
void gemm16(int M, int N, int K,
            const float* __restrict__ A, long long sAb, int lda,
            const float* __restrict__ Bm, long long sBb, int ldb,
            float* __restrict__ C, long long sCb, int ldc,
            const float* __restrict__ bias, int relu)
{
  __shared__ float sAh[16*512];
  const int tid = threadIdx.x;
  const float* Ab = A + (size_t)blockIdx.y*sAb;
  const float* Bb = Bm + (size_t)blockIdx.y*sBb;
  float* Cb = C + (size_t)blockIdx.y*sCb;
  const int m0 = blockIdx.x*16;
  const int tot = 16*K;
  for (int f = tid; f < tot; f += 256) sAh[f] = Ab[(size_t)m0*lda + f]; // lda==K
  __syncthreads();
  int c = (tid & 63)*4; int rg = tid >> 6;
  if (c >= N) return;
  float acc[4][4] = {};
  for (int k=0;k<K;k++){
    float4 bv = *reinterpret_cast<const float4*>(Bb + (size_t)k*ldb + c);
    #pragma unroll
    for (int rr=0;rr<4;rr++){
      float a = sAh[(rg*4+rr)*K + k];
      acc[rr][0] += a*bv.x; acc[rr][1] += a*bv.y; acc[rr][2] += a*bv.z; acc[rr][3] += a*bv.w;
    }
  }
  for (int rr=0;rr<4;rr++){
    int m = m0 + rg*4 + rr;
    #pragma unroll
    for (int e=0;e<4;e++){
      float v = acc[rr][e] + (bias ? bias[c+e] : 0.f);
      if (relu) v = fmaxf(v, 0.f);
      Cb[(size_t)m*ldc + c + e] = v;
    }
  }
}

// ------------------------------------------------------------ bilinear head
__global__ __launch_bounds__(256)
void bilin(const float* __restrict__ s0, const float* __restrict__ t0,
           const float* __restrict__ dis_emb, const int* __restrict__ dht,
           const int* __restrict__ dth, const float* __restrict__ Wb,
           const float* __restrict__ bb, float* __restrict__ out)
{
  __shared__ float sS[BI][33];
  __shared__ float sT[32][152];
  const int tid = threadIdx.x;
  const int bp0 = blockIdx.x*32;
  for (int f = tid; f < 32*BI; f += 256){
    int pp = f / BI, i = f % BI;
    int bp = bp0 + pp;
    float sv, tv;
    if (i < 128){ sv = s0[(size_t)bp*128 + i]; tv = t0[(size_t)bp*128 + i]; }
    else {
      sv = dis_emb[(size_t)dht[bp]*20 + (i-128)];
      tv = dis_emb[(size_t)dth[bp]*20 + (i-128)];
    }
    sS[i][pp] = sv; sT[pp][i] = tv;
  }
  __syncthreads();
  const int ppg = tid >> 5, jb = tid & 31;
  const int pp0 = ppg*4;
  const int k0 = blockIdx.y*49, kend = min(k0+49, RELK);
  for (int k = k0; k < kend; k++){
    const float* Wk = Wb + (size_t)k*BI*BI;
    float acc[4][5];
    #pragma unroll
    for (int a=0;a<4;a++) for (int b=0;b<5;b++) acc[a][b]=0.f;
    for (int i=0;i<BI;i++){
      float sv0 = sS[i][pp0], sv1 = sS[i][pp0+1], sv2 = sS[i][pp0+2], sv3 = sS[i][pp0+3];
      const float* wrow = Wk + i*BI;
      #pragma unroll
      for (int jj=0;jj<5;jj++){
        int j = jb + 32*jj;
        if (j < BI){
          float w = wrow[j];
          acc[0][jj] += sv0*w; acc[1][jj] += sv1*w; acc[2][jj] += sv2*w; acc[3][jj] += sv3*w;
        }
      }
    }
    float dot[4] = {0.f,0.f,0.f,0.f};
    #pragma unroll
    for (int jj=0;jj<5;jj++){
      int j = jb + 32*jj;
      if (j < BI){
        #pragma unroll
        for (int p4=0;p4<4;p4++) dot[p4] += acc[p4][jj]*sT[pp0+p4][j];
      }
    }
    #pragma unroll
    for (int p4=0;p4<4;p4++)
      for (int o=16;o;o>>=1) dot[p4] += __shfl_down(dot[p4], o, 32);
    if (jb == 0){
      #pragma unroll
      for (int p4=0;p4<4;p4++)
        out[(size_t)(bp0+pp0+p4)*RELK + k] = dot[p4] + bb[k];
    }
  }
}

// =========================================================== host launcher
extern "C" void kernel_launch(void* const* d_in, const int* in_sizes, int n_in,
                              void* d_out, int out_size, void* d_ws, size_t ws_size,
                              hipStream_t stream)
{
  (void)in_sizes; (void)n_in; (void)out_size; (void)ws_size;
  const int*   ctx_idx = (const int*)  d_in[0];
  const int*   pos     = (const int*)  d_in[1];
  const int*   nerI    = (const int*)  d_in[2];
  const float* h_map   = (const float*)d_in[5];
  const float* t_map   = (const float*)d_in[6];
  const int*   dht     = (const int*)  d_in[8];
  const int*   dth     = (const int*)  d_in[9];
  const float* wemb    = (const float*)d_in[10];
  const float* eemb    = (const float*)d_in[11];
  const float* nemb    = (const float*)d_in[12];
  const float* demb    = (const float*)d_in[13];
  const float* Wih0    = (const float*)d_in[14];
  const float* Whh0    = (const float*)d_in[15];
  const float* b0      = (const float*)d_in[16];
  const float* Wih1    = (const float*)d_in[17];
  const float* Whh1    = (const float*)d_in[18];
  const float* b1      = (const float*)d_in[19];
  const float* Wih2    = (const float*)d_in[20];
  const float* Whh2    = (const float*)d_in[21];
  const float* b2      = (const float*)d_in[22];
  const float* Wxi     = (const float*)d_in[23];
  const float* bxi     = (const float*)d_in[24];
  const float* Wout    = (const float*)d_in[25];
  const float* bout    = (const float*)d_in[26];
  const float* Wfin    = (const float*)d_in[27];
  const float* bfin    = (const float*)d_in[28];
  const float* Wre     = (const float*)d_in[29];
  const float* bre     = (const float*)d_in[30];
  const float* Wbili   = (const float*)d_in[31];
  const float* bbili   = (const float*)d_in[32];

  float* ws    = (float*)d_ws;
  float* sent  = ws;                    // [8][512][140]   573440
  float* Hh    = sent + 573440;         // [512][8][256]  1048576
  float* yh    = Hh + 1048576;          // [8][512][140]   573440
  float* s0b   = yh + 573440;           // [4096][128]     524288
  float* t0b   = s0b + 524288;          // [4096][128]     524288
  float* reads2= t0b + 524288;          // [2][8][4096]     65536
  float* h0g   = reads2 + 65536;        // [2][8][256]       4096
  float* h1g   = h0g + 4096;
  float* h2g   = h1g + 4096;
  float* c0g   = h2g + 4096;
  float* c1g   = c0g + 4096;
  float* c2g   = c1g + 4096;
  float* z0g   = c2g + 4096;            // [8][1024]         8192
  float* z1g   = z0g + 8192;
  float* z2g   = z1g + 8192;
  float* xig   = z2g + 8192;            // [8][10299]       82392
  float* Mb    = xig + 82392;           // [8][32][512]    131072
  float* ug    = Mb + 131072;           // [8][32]
  float* wwg   = ug + 256;
  float* pg    = wwg + 256;
  float* wrg   = pg + 256;              // [8][8][32]
  float* Lg    = wrg + 2048;            // [8][32][32]
  float* barf  = Lg + 8192;             // 256*16 + 16 ints = 4112
  float* WA_T  = barf + 4112;           // [1024][4608]   4718592
  float* W1T   = WA_T + 4718592;        // [1024][512]     524288
  float* W2T   = W1T + 524288;          // [1024][512]     524288
  float* WXIT  = W2T + 524288;          // [10299][256]   2636544
  float* WYT   = WXIT + 2636544;        // [140][4352]     609280
  float* o256  = Hh;                    // alias: Hh dead after persist
  float* ctxb  = sent;                  // alias: sent dead after persist
  int* flags = (int*)barf;
  int* gen   = flags + 4096;

  size_t stateFloats = (size_t)(WA_T - reads2);
  hipMemsetAsync(reads2, 0, stateFloats*sizeof(float), stream);

  // one-time transposed/concatenated weight copies (L3-resident afterwards)
  hipLaunchKernelGGL(k_tr, dim3(18432), dim3(256), 0, stream,
                     Wih0, Whh0, 1024, 4236, 256, 4608, (long long)4718592, WA_T);
  hipLaunchKernelGGL(k_tr, dim3(2048), dim3(256), 0, stream,
                     Wih1, Whh1, 1024, 256, 256, 512, (long long)524288, W1T);
  hipLaunchKernelGGL(k_tr, dim3(2048), dim3(256), 0, stream,
                     Wih2, Whh2, 1024, 256, 256, 512, (long long)524288, W2T);
  hipLaunchKernelGGL(k_tr, dim3(10299), dim3(256), 0, stream,
                     Wxi, Wxi, 10299, 256, 0, 256, (long long)2636544, WXIT);
  hipLaunchKernelGGL(k_tr, dim3(2380), dim3(256), 0, stream,
                     Wout, Wout, 140, 4352, 0, 4352, (long long)609280, WYT);

  hipLaunchKernelGGL(k_sent, dim3((573440+255)/256), dim3(256), 0, stream,
                     ctx_idx, pos, nerI, wemb, eemb, nemb, sent);

  hipLaunchKernelGGL(dnc_persist, dim3(NWG), dim3(TPB), 0, stream,
                     sent, WA_T, b0, W1T, b1, W2T, b2, WXIT, bxi, WYT, bout,
                     Hh, yh, reads2,
                     h0g, h1g, h2g, c0g, c1g, c2g, z0g, z1g, z2g, xig,
                     Mb, ug, wwg, pg, wrg, Lg, flags, gen);

  // out = ys @ W_final + b_final          [4096,140]x[140,256]
  hipLaunchKernelGGL(gemm16, dim3(256,1), dim3(256), 0, stream,
                     4096, 256, 140, yh, (long long)0, 140, Wfin, (long long)0, 256,
                     o256, (long long)0, 256, bfin, 0);
  // ctx = relu(out @ W_re + b_re)         [4096,256]x[256,128]
  hipLaunchKernelGGL(gemm16, dim3(256,1), dim3(256), 0, stream,
                     4096, 128, 256, o256, (long long)0, 256, Wre, (long long)0, 128,
                     ctxb, (long long)0, 128, bre, 1);
  // s0 / t0 : per-batch [512,512]x[512,128]
  hipLaunchKernelGGL(gemm16, dim3(32,8), dim3(256), 0, stream,
                     512, 128, 512, h_map, (long long)(512*512), 512,
                     ctxb, (long long)(512*128), 128,
                     s0b, (long long)(512*128), 128, (const float*)nullptr, 0);
  hipLaunchKernelGGL(gemm16, dim3(32,8), dim3(256), 0, stream,
                     512, 128, 512, t_map, (long long)(512*512), 512,
                     ctxb, (long long)(512*128), 128,
                     t0b, (long long)(512*128), 128, (const float*)nullptr, 0);
  // bilinear head
  hipLaunchKernelGGL(bilin, dim3(128,2), dim3(256), 0, stream,
                     s0b, t0b, demb, dht, dth, Wbili, bbili, (float*)d_out);
}

// Round 4
// 102437.659 us; speedup vs baseline: 1.6331x; 1.1165x over previous
//
#include <hip/hip_runtime.h>
#include <math.h>

// ---- static dims ----
#define B8      8
#define LSEQ    512
#define NWG     256
#define TPB     512
#define RELK    97
#define BI      148
#define FSTR    16        // barrier flag stride (ints) = 64B
#define LDSF    39040     // floats: sA 4160 | sRed 64 | wA 18432 | w1 2048 | w2 2048 | wxi 12288
#define LDSB    (LDSF*4)

__device__ __forceinline__ float sigf(float x){
  return (x >= 0.f) ? 1.f/(1.f + expf(-x)) : expf(x)/(1.f + expf(x));
}
__device__ __forceinline__ float spf(float x){ // softplus, stable
  return (x > 0.f) ? x + log1pf(expf(-x)) : log1pf(expf(x));
}

// ---------------------------------------------------------------- sent gather
__global__ __launch_bounds__(256)
void k_sent(const int* __restrict__ cidx, const int* __restrict__ pos,
            const int* __restrict__ ner, const float* __restrict__ wemb,
            const float* __restrict__ eemb, const float* __restrict__ nemb,
            float* __restrict__ sent)
{
  int flat = blockIdx.x*256 + threadIdx.x;
  if (flat >= B8*LSEQ*140) return;
  int d = flat % 140; int bl = flat / 140;
  float v;
  if (d < 100)      v = wemb[(size_t)cidx[bl]*100 + d];
  else if (d < 120) v = eemb[(size_t)pos[bl]*20 + (d-100)];
  else              v = nemb[(size_t)ner[bl]*20 + (d-120)];
  sent[flat] = v;
}

// ------------------------------------------- weight transpose/concat (once)
__global__ __launch_bounds__(256)
void k_tr(const float* __restrict__ A, const float* __restrict__ Bsrc,
          int N, int K1a, int K1b, int K2, long long total, float* __restrict__ T)
{
  long long i = (long long)blockIdx.x*256 + threadIdx.x;
  if (i >= total) return;
  int k = (int)(i % K2);
  long long c = i / K2;
  float v = 0.f;
  if (k < K1a)            v = A[(size_t)k*N + c];
  else if (k < K1a+K1b)   v = Bsrc[(size_t)(k-K1a)*N + c];
  T[i] = v;
}

// ---------------------------------------------------------- global barrier
// fully distributed: each wg posts seq-numbered flag; every wg polls all flags.
__device__ __forceinline__ void gbar(int* flags, int seq){
  __syncthreads();
  if (threadIdx.x == 0){
    __threadfence();
    __hip_atomic_store(&flags[blockIdx.x*FSTR], seq, __ATOMIC_RELAXED, __HIP_MEMORY_SCOPE_AGENT);
  }
  if (threadIdx.x < NWG){
    while (__hip_atomic_load(&flags[threadIdx.x*FSTR], __ATOMIC_RELAXED, __HIP_MEMORY_SCOPE_AGENT) < seq)
      __builtin_amdgcn_s_sleep(1);
  }
  __syncthreads();
  if (threadIdx.x == 0) __threadfence();
  __syncthreads();
}

// ------------------------------------- per-sample DNC memory addressing phase
// scratch = 3776 floats, overlays the sA/sRed region (dead during phase E)
__device__ void mem_phase(float* lds, const float* __restrict__ xi,
                          float* __restrict__ M, float* u_g, float* ww_g,
                          float* p_g, float* wr_g, float* L_g, float* rout)
{
  const int tid = threadIdx.x;
  float* mL  = lds;          // [32][32]
  float* mwr = lds+1024;     // [8][32]
  float* mwrn= lds+1280;
  float* mcr = lds+1536;
  float* mfw = lds+1792;
  float* mbw = lds+2048;
  float* PSI = lds+2304;
  float* UU  = lds+2336;
  float* US  = lds+2368;
  float* AA  = lds+2400;
  float* CW  = lds+2432;
  float* WWN = lds+2464;
  float* WWO = lds+2496;
  float* PP  = lds+2528;
  int*   mord= (int*)(lds+2560);   // 32 ints
  float* mh  = lds+2592;           // rb[0..7] sf[8..15] sb[16..23] fg[24..31]
  float* mpi = lds+2656;           // [8][3]
  float* msc = lds+2688;           // 64 scratch scalars
  float* q1  = lds+2752;           // 512 (shared: cw key then per-head cr key)
  float* q2  = lds+3264;           // 512 (masks)

  // ---- interface scalars / state load ----
  if (tid < 8){
    mh[tid]    = 1.f + spf(xi[4096+tid]);     // read strengths
    mh[8+tid]  = 1.f + spf(xi[10283+tid]);    // sf
    mh[16+tid] = 1.f + spf(xi[10291+tid]);    // sb
    mh[24+tid] = sigf(xi[5641+tid]);          // free gates
    float e0=xi[5651+3*tid], e1=xi[5652+3*tid], e2=xi[5653+3*tid];
    float mx=fmaxf(e0,fmaxf(e1,e2));
    float x0=expf(e0-mx), x1=expf(e1-mx), x2=expf(e2-mx);
    float inv=1.f/(x0+x1+x2);
    mpi[tid*3]=x0*inv; mpi[tid*3+1]=x1*inv; mpi[tid*3+2]=x2*inv;
  }
  if (tid==0){ msc[0]=1.f+spf(xi[4616]); msc[1]=sigf(xi[5649]); msc[2]=sigf(xi[5650]); }
  if (tid<32){ UU[tid]=u_g[tid]; WWO[tid]=ww_g[tid]; PP[tid]=p_g[tid]; }
  if (tid<256) mwr[tid]=wr_g[tid];
  mL[tid]=L_g[tid]; mL[tid+512]=L_g[tid+512];
  { float wm = 0.1f+0.9f*sigf(xi[5675+tid]); q1[tid]=xi[4104+tid]*wm; q2[tid]=wm; }
  __syncthreads();

  // psi, usage
  if (tid<32){
    float psi=1.f;
    #pragma unroll
    for (int r=0;r<8;r++) psi *= (1.f - mh[24+r]*mwr[r*32+tid]);
    PSI[tid]=psi;
    float uo=UU[tid], wo=WWO[tid];
    UU[tid]=(uo+wo-uo*wo)*psi;
  }
  __syncthreads();
  // stable ascending argsort of u
  if (tid<32){
    float un=UU[tid]; int rank=0;
    for (int m=0;m<32;m++){ float um=UU[m]; rank += (um<un)||(um==un && m<tid); }
    mord[rank]=tid;
  }
  __syncthreads();
  if (tid<32) US[tid]=UU[mord[tid]];
  __syncthreads();
  if (tid==0){ float cp=1.f; for (int j=0;j<32;j++){ AA[mord[j]]=(1.f-US[j])*cp; cp*=US[j]; } }
  __syncthreads();

  // write content weighting cw (OLD M)
  { float q=q1[tid]*q1[tid];
    for (int o=32;o;o>>=1) q += __shfl_down(q,o,64);
    if ((tid&63)==0) msc[8+(tid>>6)]=q; }
  __syncthreads();
  if (tid==0){ float q=0.f; for (int i=0;i<8;i++) q+=msc[8+i]; msc[3]=sqrtf(q); }
  __syncthreads();
  { int n=tid>>4, wsub=tid&15;
    float d=0.f,q=0.f;
    for (int i=0;i<32;i++){ int w=wsub+16*i; float m=M[(size_t)n*512+w]; float t2=m*q2[w]; d+=q1[w]*t2; q+=t2*t2; }
    for (int o=8;o;o>>=1){ d+=__shfl_down(d,o,16); q+=__shfl_down(q,o,16); }
    if (wsub==0){ float cs=d/(msc[3]*sqrtf(q)+1e-6f); CW[n]=msc[0]*cs; } }
  __syncthreads();
  if (tid==0){ float mx=-1e30f; for(int n=0;n<32;n++) mx=fmaxf(mx,CW[n]); msc[4]=mx; }
  __syncthreads();
  if (tid<32) CW[tid]=expf(CW[tid]-msc[4]);
  __syncthreads();
  if (tid==0){ float sm=0.f; for(int n=0;n<32;n++) sm+=CW[n]; msc[5]=1.f/sm; }
  __syncthreads();
  if (tid<32) CW[tid]*=msc[5];
  __syncthreads();
  // write weights
  if (tid<32) WWN[tid]=msc[2]*(msc[1]*AA[tid]+(1.f-msc[1])*CW[tid]);
  __syncthreads();
  // M dealloc + erase/write (w index == tid)
  { float er=sigf(xi[4617+tid]); float wv=xi[5129+tid];
    for (int n=0;n<32;n++){ size_t idx=(size_t)n*512+tid; float m=M[idx];
      M[idx]=m*PSI[n]*(1.f-WWN[n]*er)+WWN[n]*wv; } }
  __syncthreads();
  // link matrix (OLD p), then precedence
  for (int ii=0;ii<2;ii++){ int f=tid+512*ii; int i=f>>5, j=f&31;
    float nl=(1.f-WWN[i]-WWN[j])*mL[f]+WWN[i]*PP[j];
    mL[f]=(i==j)?0.f:nl; }
  __syncthreads();
  if (tid==0){ float sw=0.f; for(int n=0;n<32;n++) sw+=WWN[n]; msc[6]=sw; }
  __syncthreads();
  if (tid<32) PP[tid]=(1.f-msc[6])*PP[tid]+WWN[tid];
  __syncthreads();
  // fw/bw sharpened (OLD wr)
  { int r=(tid>>5)&7, i=tid&31; bool isB=(tid>=256);
    float accv=0.f;
    if (!isB){ for (int j=0;j<32;j++) accv += mL[i*32+j]*mwr[r*32+j]; }
    else     { for (int j=0;j<32;j++) accv += mL[j*32+i]*mwr[r*32+j]; }
    float sp = isB? mh[16+r] : mh[8+r];
    float e = expf(sp*logf(accv+1e-6f));
    if (!isB) mfw[r*32+i]=e; else mbw[r*32+i]=e; }
  __syncthreads();
  if (tid<16){ int r=tid&7; float sm=0.f;
    if (tid<8){ for(int n=0;n<32;n++) sm+=mfw[r*32+n]; msc[16+r]=1.f/sm; }
    else      { for(int n=0;n<32;n++) sm+=mbw[r*32+n]; msc[24+r]=1.f/sm; } }
  __syncthreads();
  { int r=(tid>>5)&7, i=tid&31; bool isB=(tid>=256);
    if (!isB) mfw[r*32+i]*=msc[16+r]; else mbw[r*32+i]*=msc[24+r]; }
  __syncthreads();
  // read content weighting cr (NEW M), one head at a time (q1/q2 reused)
  for (int r=0;r<8;r++){
    { float rm=0.1f+0.9f*sigf(xi[6187+r*512+tid]);
      q1[tid]=xi[r*512+tid]*rm; q2[tid]=rm; }
    __syncthreads();
    { float q=q1[tid]*q1[tid];
      for (int o=32;o;o>>=1) q+=__shfl_down(q,o,64);
      if ((tid&63)==0) msc[8+(tid>>6)]=q; }
    __syncthreads();
    if (tid==0){ float qq=0.f; for(int i=0;i<8;i++) qq+=msc[8+i]; msc[32]=sqrtf(qq); }
    __syncthreads();
    { int n=tid>>4, wsub=tid&15;
      float d=0.f,q=0.f;
      for (int i=0;i<32;i++){ int w=wsub+16*i; float m=M[(size_t)n*512+w]; float t2=m*q2[w]; d+=q1[w]*t2; q+=t2*t2; }
      for (int o=8;o;o>>=1){ d+=__shfl_down(d,o,16); q+=__shfl_down(q,o,16); }
      if (wsub==0){ float cs=d/(msc[32]*sqrtf(q)+1e-6f); mcr[r*32+n]=mh[r]*cs; } }
    __syncthreads();
  }
  if (tid<8){ int r=tid; float mx=-1e30f;
    for (int n=0;n<32;n++) mx=fmaxf(mx,mcr[r*32+n]);
    float sm=0.f;
    for (int n=0;n<32;n++){ float e=expf(mcr[r*32+n]-mx); mcr[r*32+n]=e; sm+=e; }
    float inv=1.f/sm;
    for (int n=0;n<32;n++) mcr[r*32+n]*=inv; }
  __syncthreads();
  // new read weights
  if (tid<256){ int r=tid>>5, n=tid&31;
    float v=mpi[r*3]*mbw[r*32+n]+mpi[r*3+1]*mcr[r*32+n]+mpi[r*3+2]*mfw[r*32+n];
    mwrn[tid]=v; wr_g[tid]=v; }
  __syncthreads();
  // reads = wr_new @ M_new
  { int r=tid>>6, wsub=tid&63;
    for (int i2=0;i2<8;i2++){ int w=wsub+64*i2;
      float accv=0.f;
      for (int n=0;n<32;n++) accv+=mwrn[r*32+n]*M[(size_t)n*512+w];
      rout[r*512+w]=accv; } }
  // state writeback
  if (tid<32){ u_g[tid]=UU[tid]; ww_g[tid]=WWN[tid]; p_g[tid]=PP[tid]; }
  L_g[tid]=mL[tid]; L_g[tid+512]=mL[tid+512];
}

// ---------------------------------------------- persistent whole-recurrence
// Recurrent weights live in LDS for all 512 steps (loaded once per wg).
__global__ __launch_bounds__(TPB, 1)
void dnc_persist(
  const float* __restrict__ sent,
  const float* __restrict__ WAg, const float* __restrict__ b0,   // [1024][4608]
  const float* __restrict__ W1g, const float* __restrict__ b1,   // [1024][512]
  const float* __restrict__ W2g, const float* __restrict__ b2,   // [1024][512]
  const float* __restrict__ WXIg,const float* __restrict__ bxi,  // [10299][256]
  const float* __restrict__ WY,  const float* __restrict__ bout, // [140][4352]
  float* __restrict__ Hh, float* __restrict__ yh,
  float* __restrict__ reads2,
  float* __restrict__ h0g, float* __restrict__ h1g, float* __restrict__ h2g,
  float* __restrict__ c0g, float* __restrict__ c1g, float* __restrict__ c2g,
  float* __restrict__ z0g, float* __restrict__ z1g, float* __restrict__ z2g,
  float* __restrict__ xig,
  float* __restrict__ Mb, float* __restrict__ ug, float* __restrict__ wwg,
  float* __restrict__ pg, float* __restrict__ wrg, float* __restrict__ Lg,
  int* flags)
{
  extern __shared__ float lds[];
  float* sA   = lds;                 // 8 x 520
  float* sRed = lds + 4160;          // 64
  float* wA   = lds + 4224;          // 4 cols x 4608
  float* w1l  = lds + 22656;         // 4 cols x 512
  float* w2l  = lds + 24704;         // 4 cols x 512
  float* wxl  = lds + 26752;         // 48 cols x 256
  const int wg  = blockIdx.x;
  const int tid = threadIdx.x;
  const int cq = tid >> 7, kq = tid & 127;   // z-gemm layout (4 cols/wg)
  const int xc = tid >> 6, xk = tid & 63;    // xi layout (48 cols/wg)
  int seq = 0;

  // ---------------- one-time: weights -> LDS ----------------
  for (int f=tid; f<18432; f+=TPB) wA[f]  = WAg[(size_t)wg*18432 + f];
  for (int f=tid; f<2048;  f+=TPB) w1l[f] = W1g[(size_t)wg*2048  + f];
  for (int f=tid; f<2048;  f+=TPB) w2l[f] = W2g[(size_t)wg*2048  + f];
  for (int f=tid; f<12288; f+=TPB){
    int cl = f>>8, k = f&255; int col = wg*48 + cl;
    wxl[f] = (col < 10299) ? WXIg[(size_t)col*256 + k] : 0.f;
  }
  const bool isy = (wg >= 8 && wg < 148);
  const float* wcolY = WY + (size_t)(isy ? (wg-8) : 0)*4352;
  __syncthreads();

  #pragma unroll 1
  for (int t=0; t<LSEQ; t++){
    const int rp = t&1, wp = rp^1, pprev = (t+1)&1;
    const float* readsPrev = reads2 + (size_t)pprev*32768;

    // ================= phase A: z0 gemm (K=4492 padded to 4608) =========
    {
      const float* h0p = h0g + pprev*2048;
      float acc[8] = {0,0,0,0,0,0,0,0};
      float av[8];
      #pragma unroll
      for (int s=0;s<8;s++){
        int kg = tid;
        av[s] = (kg<140) ? sent[((size_t)s*512 + t)*140 + kg]
                         : readsPrev[s*4096 + kg - 140];
      }
      #pragma unroll 1
      for (int ch=0; ch<9; ch++){
        __syncthreads();
        #pragma unroll
        for (int s=0;s<8;s++) sA[s*520 + tid] = av[s];
        __syncthreads();
        if (ch < 8){
          int kg = (ch+1)*512 + tid;
          #pragma unroll
          for (int s=0;s<8;s++){
            float v;
            if (kg < 140)       v = sent[((size_t)s*512 + t)*140 + kg];
            else if (kg < 4236) v = readsPrev[s*4096 + kg - 140];
            else if (kg < 4492) v = h0p[s*256 + (kg-4236)];
            else                v = 0.f;
            av[s]=v;
          }
        }
        float4 wv = *reinterpret_cast<const float4*>(&wA[cq*4608 + ch*512 + (kq<<2)]);
        #pragma unroll
        for (int s=0;s<8;s++){
          float4 a = *reinterpret_cast<const float4*>(&sA[s*520 + (kq<<2)]);
          acc[s] += a.x*wv.x + a.y*wv.y + a.z*wv.z + a.w*wv.w;
        }
      }
      #pragma unroll
      for (int o=32;o;o>>=1)
        #pragma unroll
        for (int s=0;s<8;s++) acc[s]+=__shfl_down(acc[s],o,64);
      if ((tid&63)==0){ int wv2=tid>>6;
        #pragma unroll
        for (int s=0;s<8;s++) sRed[wv2*8+s]=acc[s]; }
      __syncthreads();
      if (tid<32){ int c=tid>>3, s=tid&7;
        z0g[s*1024 + wg*4 + c] = sRed[c*16+s] + sRed[c*16+8+s] + b0[wg*4+c]; }
    }
    gbar(flags,++seq);

    // ================= phase B: cell0 + z1 gemm =========================
    {
      float4 w1v = *reinterpret_cast<const float4*>(&w1l[cq*512 + (kq<<2)]);
      if (tid<256){
        int j=tid;
        #pragma unroll
        for (int s=0;s<8;s++){
          float zi=z0g[s*1024+j], zf=z0g[s*1024+256+j], zg=z0g[s*1024+512+j], zo=z0g[s*1024+768+j];
          float cold=c0g[rp*2048+s*256+j];
          float cn=sigf(zf)*cold+sigf(zi)*tanhf(zg);
          float h=sigf(zo)*tanhf(cn);
          sA[s*520+j]=h;
          if (wg==8){ c0g[wp*2048+s*256+j]=cn; h0g[rp*2048+s*256+j]=h; }
        }
      } else {
        int j=tid-256;
        const float* h1p = h1g + pprev*2048;
        #pragma unroll
        for (int s=0;s<8;s++) sA[s*520+256+j]=h1p[s*256+j];
      }
      __syncthreads();
      float acc[8]={0,0,0,0,0,0,0,0};
      #pragma unroll
      for (int s=0;s<8;s++){
        float4 a=*reinterpret_cast<const float4*>(&sA[s*520+(kq<<2)]);
        acc[s]+=a.x*w1v.x+a.y*w1v.y+a.z*w1v.z+a.w*w1v.w;
      }
      #pragma unroll
      for (int o=32;o;o>>=1)
        #pragma unroll
        for (int s=0;s<8;s++) acc[s]+=__shfl_down(acc[s],o,64);
      if ((tid&63)==0){ int wv2=tid>>6;
        #pragma unroll
        for (int s=0;s<8;s++) sRed[wv2*8+s]=acc[s]; }
      __syncthreads();
      if (tid<32){ int c=tid>>3, s=tid&7;
        z1g[s*1024 + wg*4 + c] = sRed[c*16+s] + sRed[c*16+8+s] + b1[wg*4+c]; }
    }
    gbar(flags,++seq);

    // ================= phase C: cell1 + z2 gemm =========================
    {
      float4 w2v = *reinterpret_cast<const float4*>(&w2l[cq*512 + (kq<<2)]);
      if (tid<256){
        int j=tid;
        #pragma unroll
        for (int s=0;s<8;s++){
          float zi=z1g[s*1024+j], zf=z1g[s*1024+256+j], zg=z1g[s*1024+512+j], zo=z1g[s*1024+768+j];
          float cold=c1g[rp*2048+s*256+j];
          float cn=sigf(zf)*cold+sigf(zi)*tanhf(zg);
          float h=sigf(zo)*tanhf(cn);
          sA[s*520+j]=h;
          if (wg==8){ c1g[wp*2048+s*256+j]=cn; h1g[rp*2048+s*256+j]=h; }
        }
      } else {
        int j=tid-256;
        const float* h2p = h2g + pprev*2048;
        #pragma unroll
        for (int s=0;s<8;s++) sA[s*520+256+j]=h2p[s*256+j];
      }
      __syncthreads();
      float acc[8]={0,0,0,0,0,0,0,0};
      #pragma unroll
      for (int s=0;s<8;s++){
        float4 a=*reinterpret_cast<const float4*>(&sA[s*520+(kq<<2)]);
        acc[s]+=a.x*w2v.x+a.y*w2v.y+a.z*w2v.z+a.w*w2v.w;
      }
      #pragma unroll
      for (int o=32;o;o>>=1)
        #pragma unroll
        for (int s=0;s<8;s++) acc[s]+=__shfl_down(acc[s],o,64);
      if ((tid&63)==0){ int wv2=tid>>6;
        #pragma unroll
        for (int s=0;s<8;s++) sRed[wv2*8+s]=acc[s]; }
      __syncthreads();
      if (tid<32){ int c=tid>>3, s=tid&7;
        z2g[s*1024 + wg*4 + c] = sRed[c*16+s] + sRed[c*16+8+s] + b2[wg*4+c]; }
    }
    gbar(flags,++seq);

    // ================= phase D: cell2 + xi gemm =========================
    {
      if (tid<256){
        int j=tid;
        #pragma unroll
        for (int s=0;s<8;s++){
          float zi=z2g[s*1024+j], zf=z2g[s*1024+256+j], zg=z2g[s*1024+512+j], zo=z2g[s*1024+768+j];
          float cold=c2g[rp*2048+s*256+j];
          float cn=sigf(zf)*cold+sigf(zi)*tanhf(zg);
          float h2=sigf(zo)*tanhf(cn);
          float hc=fminf(fmaxf(h2,-20.f),20.f);
          sA[s*520+j]=hc;
          if (wg==8){ c2g[wp*2048+s*256+j]=cn; h2g[rp*2048+s*256+j]=h2;
                      Hh[((size_t)t*8+s)*256+j]=hc; }
        }
      }
      __syncthreads();
      float accx[6][8];
      #pragma unroll
      for (int cc=0;cc<6;cc++)
        #pragma unroll
        for (int s=0;s<8;s++) accx[cc][s]=0.f;
      #pragma unroll
      for (int s=0;s<8;s++){
        float4 a = *reinterpret_cast<const float4*>(&sA[s*520 + (xk<<2)]);
        #pragma unroll
        for (int cc=0;cc<6;cc++){
          float4 wv = *reinterpret_cast<const float4*>(&wxl[(xc*6+cc)*256 + (xk<<2)]);
          accx[cc][s] += a.x*wv.x + a.y*wv.y + a.z*wv.z + a.w*wv.w;
        }
      }
      #pragma unroll
      for (int o=32;o;o>>=1)
        #pragma unroll
        for (int cc=0;cc<6;cc++)
          #pragma unroll
          for (int s=0;s<8;s++) accx[cc][s]+=__shfl_down(accx[cc][s],o,64);
      if ((tid&63)==0){
        #pragma unroll
        for (int cc=0;cc<6;cc++){
          int col = wg*48 + xc*6 + cc;
          if (col < 10299){
            #pragma unroll
            for (int s=0;s<8;s++) xig[(size_t)s*10299+col]=accx[cc][s]+bxi[col];
          }
        }
      }
    }
    gbar(flags,++seq);

    // ================= phase E: memory update (wg<8) + y(t-1) ==========
    if (wg < 8){
      mem_phase(lds, xig + (size_t)wg*10299, Mb + (size_t)wg*16384,
                ug+wg*32, wwg+wg*32, pg+wg*32, wrg+wg*256, Lg+wg*1024,
                reads2 + (size_t)rp*32768 + wg*4096);
    } else if (isy && t > 0){
      int ty = t-1;
      const float* rdp = reads2 + (size_t)(ty&1)*32768;
      float wy[9];
      #pragma unroll
      for (int ch=0;ch<9;ch++){ int k=ch*512+tid; wy[ch]=(k<4352)? wcolY[k] : 0.f; }
      float acy[8]={0,0,0,0,0,0,0,0};
      #pragma unroll
      for (int ch=0;ch<9;ch++){
        int kg=ch*512+tid;
        #pragma unroll
        for (int s=0;s<8;s++){
          float a;
          if (kg<256)       a=Hh[((size_t)ty*8+s)*256+kg];
          else if (kg<4352) a=rdp[s*4096+kg-256];
          else              a=0.f;
          acy[s]+=a*wy[ch];
        }
      }
      #pragma unroll
      for (int o=32;o;o>>=1)
        #pragma unroll
        for (int s=0;s<8;s++) acy[s]+=__shfl_down(acy[s],o,64);
      if ((tid&63)==0){ int wv2=tid>>6;
        #pragma unroll
        for (int s=0;s<8;s++) sRed[wv2*8+s]=acy[s]; }
      __syncthreads();
      if (tid<8){ float v=0.f;
        #pragma unroll
        for (int w=0;w<8;w++) v+=sRed[w*8+tid];
        yh[((size_t)tid*512+ty)*140+(wg-8)]=v+bout[wg-8]; }
    }
    gbar(flags,++seq);
  }

  // ---------------- final y(511) ----------------
  if (isy){
    int ty = 511;
    const float* rdp = reads2 + (size_t)(ty&1)*32768;
    float wy[9];
    #pragma unroll
    for (int ch=0;ch<9;ch++){ int k=ch*512+tid; wy[ch]=(k<4352)? wcolY[k] : 0.f; }
    float acy[8]={0,0,0,0,0,0,0,0};
    #pragma unroll
    for (int ch=0;ch<9;ch++){
      int kg=ch*512+tid;
      #pragma unroll
      for (int s=0;s<8;s++){
        float a;
        if (kg<256)       a=Hh[((size_t)ty*8+s)*256+kg];
        else if (kg<4352) a=rdp[s*4096+kg-256];
        else              a=0.f;
        acy[s]+=a*wy[ch];
      }
    }
    #pragma unroll
    for (int o=32;o;o>>=1)
      #pragma unroll
      for (int s=0;s<8;s++) acy[s]+=__shfl_down(acy[s],o,64);
    if ((tid&63)==0){ int wv2=tid>>6;
      #pragma unroll
      for (int s=0;s<8;s++) sRed[wv2*8+s]=acy[s]; }
    __syncthreads();
    if (tid<8){ float v=0.f;
      #pragma unroll
      for (int w=0;w<8;w++) v+=sRed[w*8+tid];
      yh[((size_t)tid*512+ty)*140+(wg-8)]=v+bout[wg-8]; }
  }
}

// ---------------------------------------- generic 16-row tiled gemm (lda==K)
__global__ __launch_bounds__(256)
void gemm16(int M, int N, int K,
            const float* __restrict__ A, long long sAb, int lda,
            const float* __restrict__ Bm, long long sBb, int ldb,
            float* __restrict__ C, long long sCb, int ldc,
            const float* __restrict__ bias, int relu)
{
  __shared__ float sAh[16*512];
  const int tid = threadIdx.x;
  const float* Ab = A + (size_t)blockIdx.y*sAb;
  const float* Bb = Bm + (size_t)blockIdx.y*sBb;
  float* Cb = C + (size_t)blockIdx.y*sCb;
  const int m0 = blockIdx.x*16;
  const int tot = 16*K;
  for (int f = tid; f < tot; f += 256) sAh[f] = Ab[(size_t)m0*lda + f]; // lda==K
  __syncthreads();
  int c = (tid & 63)*4; int rg = tid >> 6;
  if (c >= N) return;
  float acc[4][4] = {};
  for (int k=0;k<K;k++){
    float4 bv = *reinterpret_cast<const float4*>(Bb + (size_t)k*ldb + c);
    #pragma unroll
    for (int rr=0;rr<4;rr++){
      float a = sAh[(rg*4+rr)*K + k];
      acc[rr][0] += a*bv.x; acc[rr][1] += a*bv.y; acc[rr][2] += a*bv.z; acc[rr][3] += a*bv.w;
    }
  }
  for (int rr=0;rr<4;rr++){
    int m = m0 + rg*4 + rr;
    #pragma unroll
    for (int e=0;e<4;e++){
      float v = acc[rr][e] + (bias ? bias[c+e] : 0.f);
      if (relu) v = fmaxf(v, 0.f);
      Cb[(size_t)m*ldc + c + e] = v;
    }
  }
}

// ------------------------------------------------------------ bilinear head
__global__ __launch_bounds__(256)
void bilin(const float* __restrict__ s0, const float* __restrict__ t0,
           const float* __restrict__ dis_emb, const int* __restrict__ dht,
           const int* __restrict__ dth, const float* __restrict__ Wb,
           const float* __restrict__ bb, float* __restrict__ out)
{
  __shared__ float sS[BI][33];
  __shared__ float sT[32][152];
  const int tid = threadIdx.x;
  const int bp0 = blockIdx.x*32;
  for (int f = tid; f < 32*BI; f += 256){
    int pp = f / BI, i = f % BI;
    int bp = bp0 + pp;
    float sv, tv;
    if (i < 128){ sv = s0[(size_t)bp*128 + i]; tv = t0[(size_t)bp*128 + i]; }
    else {
      sv = dis_emb[(size_t)dht[bp]*20 + (i-128)];
      tv = dis_emb[(size_t)dth[bp]*20 + (i-128)];
    }
    sS[i][pp] = sv; sT[pp][i] = tv;
  }
  __syncthreads();
  const int ppg = tid >> 5, jb = tid & 31;
  const int pp0 = ppg*4;
  const int k0 = blockIdx.y*49, kend = min(k0+49, RELK);
  for (int k = k0; k < kend; k++){
    const float* Wk = Wb + (size_t)k*BI*BI;
    float acc[4][5];
    #pragma unroll
    for (int a=0;a<4;a++) for (int b=0;b<5;b++) acc[a][b]=0.f;
    for (int i=0;i<BI;i++){
      float sv0 = sS[i][pp0], sv1 = sS[i][pp0+1], sv2 = sS[i][pp0+2], sv3 = sS[i][pp0+3];
      const float* wrow = Wk + i*BI;
      #pragma unroll
      for (int jj=0;jj<5;jj++){
        int j = jb + 32*jj;
        if (j < BI){
          float w = wrow[j];
          acc[0][jj] += sv0*w; acc[1][jj] += sv1*w; acc[2][jj] += sv2*w; acc[3][jj] += sv3*w;
        }
      }
    }
    float dot[4] = {0.f,0.f,0.f,0.f};
    #pragma unroll
    for (int jj=0;jj<5;jj++){
      int j = jb + 32*jj;
      if (j < BI){
        #pragma unroll
        for (int p4=0;p4<4;p4++) dot[p4] += acc[p4][jj]*sT[pp0+p4][j];
      }
    }
    #pragma unroll
    for (int p4=0;p4<4;p4++)
      for (int o=16;o;o>>=1) dot[p4] += __shfl_down(dot[p4], o, 32);
    if (jb == 0){
      #pragma unroll
      for (int p4=0;p4<4;p4++)
        out[(size_t)(bp0+pp0+p4)*RELK + k] = dot[p4] + bb[k];
    }
  }
}

// =========================================================== host launcher
extern "C" void kernel_launch(void* const* d_in, const int* in_sizes, int n_in,
                              void* d_out, int out_size, void* d_ws, size_t ws_size,
                              hipStream_t stream)
{
  (void)in_sizes; (void)n_in; (void)out_size; (void)ws_size;
  const int*   ctx_idx = (const int*)  d_in[0];
  const int*   pos     = (const int*)  d_in[1];
  const int*   nerI    = (const int*)  d_in[2];
  const float* h_map   = (const float*)d_in[5];
  const float* t_map   = (const float*)d_in[6];
  const int*   dht     = (const int*)  d_in[8];
  const int*   dth     = (const int*)  d_in[9];
  const float* wemb    = (const float*)d_in[10];
  const float* eemb    = (const float*)d_in[11];
  const float* nemb    = (const float*)d_in[12];
  const float* demb    = (const float*)d_in[13];
  const float* Wih0    = (const float*)d_in[14];
  const float* Whh0    = (const float*)d_in[15];
  const float* b0      = (const float*)d_in[16];
  const float* Wih1    = (const float*)d_in[17];
  const float* Whh1    = (const float*)d_in[18];
  const float* b1      = (const float*)d_in[19];
  const float* Wih2    = (const float*)d_in[20];
  const float* Whh2    = (const float*)d_in[21];
  const float* b2      = (const float*)d_in[22];
  const float* Wxi     = (const float*)d_in[23];
  const float* bxi     = (const float*)d_in[24];
  const float* Wout    = (const float*)d_in[25];
  const float* bout    = (const float*)d_in[26];
  const float* Wfin    = (const float*)d_in[27];
  const float* bfin    = (const float*)d_in[28];
  const float* Wre     = (const float*)d_in[29];
  const float* bre     = (const float*)d_in[30];
  const float* Wbili   = (const float*)d_in[31];
  const float* bbili   = (const float*)d_in[32];

  float* ws    = (float*)d_ws;
  float* sent  = ws;                    // [8][512][140]   573440
  float* Hh    = sent + 573440;         // [512][8][256]  1048576
  float* yh    = Hh + 1048576;          // [8][512][140]   573440
  float* s0b   = yh + 573440;           // [4096][128]     524288
  float* t0b   = s0b + 524288;          // [4096][128]     524288
  float* reads2= t0b + 524288;          // [2][8][4096]     65536
  float* h0g   = reads2 + 65536;        // [2][8][256]       4096
  float* h1g   = h0g + 4096;
  float* h2g   = h1g + 4096;
  float* c0g   = h2g + 4096;
  float* c1g   = c0g + 4096;
  float* c2g   = c1g + 4096;
  float* z0g   = c2g + 4096;            // [8][1024]         8192
  float* z1g   = z0g + 8192;
  float* z2g   = z1g + 8192;
  float* xig   = z2g + 8192;            // [8][10299]       82392
  float* Mb    = xig + 82392;           // [8][32][512]    131072
  float* ug    = Mb + 131072;           // [8][32]
  float* wwg   = ug + 256;
  float* pg    = wwg + 256;
  float* wrg   = pg + 256;              // [8][8][32]
  float* Lg    = wrg + 2048;            // [8][32][32]
  float* barf  = Lg + 8192;             // 256*16 ints
  float* WA_T  = barf + 4112;           // [1024][4608]   4718592
  float* W1T   = WA_T + 4718592;        // [1024][512]     524288
  float* W2T   = W1T + 524288;          // [1024][512]     524288
  float* WXIT  = W2T + 524288;          // [10299][256]   2636544
  float* WYT   = WXIT + 2636544;        // [140][4352]     609280
  float* o256  = Hh;                    // alias: Hh dead after persist+gemm use
  float* ctxb  = sent;                  // alias: sent dead after persist
  int* flags = (int*)barf;

  size_t stateFloats = (size_t)(WA_T - reads2);
  hipMemsetAsync(reads2, 0, stateFloats*sizeof(float), stream);

  // one-time transposed/concatenated weight copies
  hipLaunchKernelGGL(k_tr, dim3(18432), dim3(256), 0, stream,
                     Wih0, Whh0, 1024, 4236, 256, 4608, (long long)4718592, WA_T);
  hipLaunchKernelGGL(k_tr, dim3(2048), dim3(256), 0, stream,
                     Wih1, Whh1, 1024, 256, 256, 512, (long long)524288, W1T);
  hipLaunchKernelGGL(k_tr, dim3(2048), dim3(256), 0, stream,
                     Wih2, Whh2, 1024, 256, 256, 512, (long long)524288, W2T);
  hipLaunchKernelGGL(k_tr, dim3(10299), dim3(256), 0, stream,
                     Wxi, Wxi, 10299, 256, 0, 256, (long long)2636544, WXIT);
  hipLaunchKernelGGL(k_tr, dim3(2380), dim3(256), 0, stream,
                     Wout, Wout, 140, 4352, 0, 4352, (long long)609280, WYT);

  hipLaunchKernelGGL(k_sent, dim3((573440+255)/256), dim3(256), 0, stream,
                     ctx_idx, pos, nerI, wemb, eemb, nemb, sent);

  // allow >64KB dynamic LDS (host-side attribute set; not a stream op)
  hipFuncSetAttribute(reinterpret_cast<const void*>(dnc_persist),
                      hipFuncAttributeMaxDynamicSharedMemorySize, LDSB);

  hipLaunchKernelGGL(dnc_persist, dim3(NWG), dim3(TPB), LDSB, stream,
                     sent, WA_T, b0, W1T, b1, W2T, b2, WXIT, bxi, WYT, bout,
                     Hh, yh, reads2,
                     h0g, h1g, h2g, c0g, c1g, c2g, z0g, z1g, z2g, xig,
                     Mb, ug, wwg, pg, wrg, Lg, flags);

  // out = ys @ W_final + b_final          [4096,140]x[140,256]
  hipLaunchKernelGGL(gemm16, dim3(256,1), dim3(256), 0, stream,
                     4096, 256, 140, yh, (long long)0, 140, Wfin, (long long)0, 256,
                     o256, (long long)0, 256, bfin, 0);
  // ctx = relu(out @ W_re + b_re)         [4096,256]x[256,128]
  hipLaunchKernelGGL(gemm16, dim3(256,1), dim3(256), 0, stream,
                     4096, 128, 256, o256, (long long)0, 256, Wre, (long long)0, 128,
                     ctxb, (long long)0, 128, bre, 1);
  // s0 / t0 : per-batch [512,512]x[512,128]
  hipLaunchKernelGGL(gemm16, dim3(32,8), dim3(256), 0, stream,
                     512, 128, 512, h_map, (long long)(512*512), 512,
                     ctxb, (long long)(512*128), 128,
                     s0b, (long long)(512*128), 128, (const float*)nullptr, 0);
  hipLaunchKernelGGL(gemm16, dim3(32,8), dim3(256), 0, stream,
                     512, 128, 512, t_map, (long long)(512*512), 512,
                     ctxb, (long long)(512*128), 128,
                     t0b, (long long)(512*128), 128, (const float*)nullptr, 0);
  // bilinear head
  hipLaunchKernelGGL(bilin, dim3(128,2), dim3(256), 0, stream,
                     s0b, t0b, demb, dht, dth, Wbili, bbili, (float*)d_out);
}

// Round 5
// 88910.114 us; speedup vs baseline: 1.8816x; 1.1521x over previous
//
#include <hip/hip_runtime.h>
#include <math.h>

// ---- static dims ----
#define B8      8
#define LSEQ    512
#define NWG     256
#define TPB     512
#define RELK    97
#define BI      148
#define FSTR    16        // barrier flag stride (ints) = 64B
#define LDSF    39040     // floats: sA 4160 | sRed 64 | wA 18432 | w1 2048 | w2 2048 | wxi 12288
#define LDSB    (LDSF*4)

__device__ __forceinline__ float sigf(float x){
  return (x >= 0.f) ? 1.f/(1.f + expf(-x)) : expf(x)/(1.f + expf(x));
}
__device__ __forceinline__ float spf(float x){ // softplus, stable
  return (x > 0.f) ? x + log1pf(expf(-x)) : log1pf(expf(x));
}

// agent-scope (L2-bypassing, L3-coherent) element transfer for cross-wg data
__device__ __forceinline__ float agld(const float* p){
  return __hip_atomic_load(p, __ATOMIC_RELAXED, __HIP_MEMORY_SCOPE_AGENT);
}
__device__ __forceinline__ void agst(float* p, float v){
  __hip_atomic_store(p, v, __ATOMIC_RELAXED, __HIP_MEMORY_SCOPE_AGENT);
}

// ---------------------------------------------------------------- sent gather
__global__ __launch_bounds__(256)
void k_sent(const int* __restrict__ cidx, const int* __restrict__ pos,
            const int* __restrict__ ner, const float* __restrict__ wemb,
            const float* __restrict__ eemb, const float* __restrict__ nemb,
            float* __restrict__ sent)
{
  int flat = blockIdx.x*256 + threadIdx.x;
  if (flat >= B8*LSEQ*140) return;
  int d = flat % 140; int bl = flat / 140;
  float v;
  if (d < 100)      v = wemb[(size_t)cidx[bl]*100 + d];
  else if (d < 120) v = eemb[(size_t)pos[bl]*20 + (d-100)];
  else              v = nemb[(size_t)ner[bl]*20 + (d-120)];
  sent[flat] = v;
}

// ------------------------------------------- weight transpose/concat (once)
__global__ __launch_bounds__(256)
void k_tr(const float* __restrict__ A, const float* __restrict__ Bsrc,
          int N, int K1a, int K1b, int K2, long long total, float* __restrict__ T)
{
  long long i = (long long)blockIdx.x*256 + threadIdx.x;
  if (i >= total) return;
  int k = (int)(i % K2);
  long long c = i / K2;
  float v = 0.f;
  if (k < K1a)            v = A[(size_t)k*N + c];
  else if (k < K1a+K1b)   v = Bsrc[(size_t)(k-K1a)*N + c];
  T[i] = v;
}

// ---------------------------------------------------------- global barrier
// fence-free: hand-rolled release (vmcnt drain) + agent atomics.
// wg0 gathers 256 flags (1 poller/line), posts 32 replicated gen lines
// (<=8 pollers/line). No threadfence -> L2 never invalidated.
__device__ __forceinline__ void gbar(int* flags, int* genrep, int seq){
  __syncthreads();
  const int tid = threadIdx.x;
  const int bid = blockIdx.x;
  if (tid == 0){
    asm volatile("s_waitcnt vmcnt(0)" ::: "memory");
    __hip_atomic_store(&flags[bid*FSTR], seq, __ATOMIC_RELAXED, __HIP_MEMORY_SCOPE_AGENT);
  }
  if (bid == 0){
    if (tid < NWG){
      while (__hip_atomic_load(&flags[tid*FSTR], __ATOMIC_RELAXED, __HIP_MEMORY_SCOPE_AGENT) < seq)
        __builtin_amdgcn_s_sleep(2);
    }
    __syncthreads();
    if (tid < 32)
      __hip_atomic_store(&genrep[tid*FSTR], seq, __ATOMIC_RELAXED, __HIP_MEMORY_SCOPE_AGENT);
  } else if (tid == 0){
    while (__hip_atomic_load(&genrep[(bid & 31)*FSTR], __ATOMIC_RELAXED, __HIP_MEMORY_SCOPE_AGENT) < seq)
      __builtin_amdgcn_s_sleep(2);
  }
  __syncthreads();
}

// ------------------------------------- per-sample DNC memory addressing phase
// scratch = 3776 floats, overlays the sA/sRed region (dead during phase E)
// xi is cross-wg (written phase D by all wgs) -> agent loads; M/u/ww/p/wr/L private.
__device__ void mem_phase(float* lds, const float* __restrict__ xi,
                          float* __restrict__ M, float* u_g, float* ww_g,
                          float* p_g, float* wr_g, float* L_g, float* rout)
{
  const int tid = threadIdx.x;
  float* mL  = lds;          // [32][32]
  float* mwr = lds+1024;     // [8][32]
  float* mwrn= lds+1280;
  float* mcr = lds+1536;
  float* mfw = lds+1792;
  float* mbw = lds+2048;
  float* PSI = lds+2304;
  float* UU  = lds+2336;
  float* US  = lds+2368;
  float* AA  = lds+2400;
  float* CW  = lds+2432;
  float* WWN = lds+2464;
  float* WWO = lds+2496;
  float* PP  = lds+2528;
  int*   mord= (int*)(lds+2560);   // 32 ints
  float* mh  = lds+2592;           // rb[0..7] sf[8..15] sb[16..23] fg[24..31]
  float* mpi = lds+2656;           // [8][3]
  float* msc = lds+2688;           // 64 scratch scalars
  float* q1  = lds+2752;           // 512
  float* q2  = lds+3264;           // 512

  // ---- interface scalars / state load ----
  if (tid < 8){
    mh[tid]    = 1.f + spf(agld(&xi[4096+tid]));     // read strengths
    mh[8+tid]  = 1.f + spf(agld(&xi[10283+tid]));    // sf
    mh[16+tid] = 1.f + spf(agld(&xi[10291+tid]));    // sb
    mh[24+tid] = sigf(agld(&xi[5641+tid]));          // free gates
    float e0=agld(&xi[5651+3*tid]), e1=agld(&xi[5652+3*tid]), e2=agld(&xi[5653+3*tid]);
    float mx=fmaxf(e0,fmaxf(e1,e2));
    float x0=expf(e0-mx), x1=expf(e1-mx), x2=expf(e2-mx);
    float inv=1.f/(x0+x1+x2);
    mpi[tid*3]=x0*inv; mpi[tid*3+1]=x1*inv; mpi[tid*3+2]=x2*inv;
  }
  if (tid==0){ msc[0]=1.f+spf(agld(&xi[4616])); msc[1]=sigf(agld(&xi[5649])); msc[2]=sigf(agld(&xi[5650])); }
  if (tid<32){ UU[tid]=u_g[tid]; WWO[tid]=ww_g[tid]; PP[tid]=p_g[tid]; }
  if (tid<256) mwr[tid]=wr_g[tid];
  mL[tid]=L_g[tid]; mL[tid+512]=L_g[tid+512];
  { float wm = 0.1f+0.9f*sigf(agld(&xi[5675+tid])); q1[tid]=agld(&xi[4104+tid])*wm; q2[tid]=wm; }
  __syncthreads();

  // psi, usage
  if (tid<32){
    float psi=1.f;
    #pragma unroll
    for (int r=0;r<8;r++) psi *= (1.f - mh[24+r]*mwr[r*32+tid]);
    PSI[tid]=psi;
    float uo=UU[tid], wo=WWO[tid];
    UU[tid]=(uo+wo-uo*wo)*psi;
  }
  __syncthreads();
  // stable ascending argsort of u
  if (tid<32){
    float un=UU[tid]; int rank=0;
    for (int m=0;m<32;m++){ float um=UU[m]; rank += (um<un)||(um==un && m<tid); }
    mord[rank]=tid;
  }
  __syncthreads();
  if (tid<32) US[tid]=UU[mord[tid]];
  __syncthreads();
  if (tid==0){ float cp=1.f; for (int j=0;j<32;j++){ AA[mord[j]]=(1.f-US[j])*cp; cp*=US[j]; } }
  __syncthreads();

  // write content weighting cw (OLD M)
  { float q=q1[tid]*q1[tid];
    for (int o=32;o;o>>=1) q += __shfl_down(q,o,64);
    if ((tid&63)==0) msc[8+(tid>>6)]=q; }
  __syncthreads();
  if (tid==0){ float q=0.f; for (int i=0;i<8;i++) q+=msc[8+i]; msc[3]=sqrtf(q); }
  __syncthreads();
  { int n=tid>>4, wsub=tid&15;
    float d=0.f,q=0.f;
    for (int i=0;i<32;i++){ int w=wsub+16*i; float m=M[(size_t)n*512+w]; float t2=m*q2[w]; d+=q1[w]*t2; q+=t2*t2; }
    for (int o=8;o;o>>=1){ d+=__shfl_down(d,o,16); q+=__shfl_down(q,o,16); }
    if (wsub==0){ float cs=d/(msc[3]*sqrtf(q)+1e-6f); CW[n]=msc[0]*cs; } }
  __syncthreads();
  if (tid==0){ float mx=-1e30f; for(int n=0;n<32;n++) mx=fmaxf(mx,CW[n]); msc[4]=mx; }
  __syncthreads();
  if (tid<32) CW[tid]=expf(CW[tid]-msc[4]);
  __syncthreads();
  if (tid==0){ float sm=0.f; for(int n=0;n<32;n++) sm+=CW[n]; msc[5]=1.f/sm; }
  __syncthreads();
  if (tid<32) CW[tid]*=msc[5];
  __syncthreads();
  // write weights
  if (tid<32) WWN[tid]=msc[2]*(msc[1]*AA[tid]+(1.f-msc[1])*CW[tid]);
  __syncthreads();
  // M dealloc + erase/write (w index == tid)
  { float er=sigf(agld(&xi[4617+tid])); float wv=agld(&xi[5129+tid]);
    for (int n=0;n<32;n++){ size_t idx=(size_t)n*512+tid; float m=M[idx];
      M[idx]=m*PSI[n]*(1.f-WWN[n]*er)+WWN[n]*wv; } }
  __syncthreads();
  // link matrix (OLD p), then precedence
  for (int ii=0;ii<2;ii++){ int f=tid+512*ii; int i=f>>5, j=f&31;
    float nl=(1.f-WWN[i]-WWN[j])*mL[f]+WWN[i]*PP[j];
    mL[f]=(i==j)?0.f:nl; }
  __syncthreads();
  if (tid==0){ float sw=0.f; for(int n=0;n<32;n++) sw+=WWN[n]; msc[6]=sw; }
  __syncthreads();
  if (tid<32) PP[tid]=(1.f-msc[6])*PP[tid]+WWN[tid];
  __syncthreads();
  // fw/bw sharpened (OLD wr)
  { int r=(tid>>5)&7, i=tid&31; bool isB=(tid>=256);
    float accv=0.f;
    if (!isB){ for (int j=0;j<32;j++) accv += mL[i*32+j]*mwr[r*32+j]; }
    else     { for (int j=0;j<32;j++) accv += mL[j*32+i]*mwr[r*32+j]; }
    float sp = isB? mh[16+r] : mh[8+r];
    float e = expf(sp*logf(accv+1e-6f));
    if (!isB) mfw[r*32+i]=e; else mbw[r*32+i]=e; }
  __syncthreads();
  if (tid<16){ int r=tid&7; float sm=0.f;
    if (tid<8){ for(int n=0;n<32;n++) sm+=mfw[r*32+n]; msc[16+r]=1.f/sm; }
    else      { for(int n=0;n<32;n++) sm+=mbw[r*32+n]; msc[24+r]=1.f/sm; } }
  __syncthreads();
  { int r=(tid>>5)&7, i=tid&31; bool isB=(tid>=256);
    if (!isB) mfw[r*32+i]*=msc[16+r]; else mbw[r*32+i]*=msc[24+r]; }
  __syncthreads();
  // read content weighting cr (NEW M), one head at a time (q1/q2 reused)
  for (int r=0;r<8;r++){
    { float rm=0.1f+0.9f*sigf(agld(&xi[6187+r*512+tid]));
      q1[tid]=agld(&xi[r*512+tid])*rm; q2[tid]=rm; }
    __syncthreads();
    { float q=q1[tid]*q1[tid];
      for (int o=32;o;o>>=1) q+=__shfl_down(q,o,64);
      if ((tid&63)==0) msc[8+(tid>>6)]=q; }
    __syncthreads();
    if (tid==0){ float qq=0.f; for(int i=0;i<8;i++) qq+=msc[8+i]; msc[32]=sqrtf(qq); }
    __syncthreads();
    { int n=tid>>4, wsub=tid&15;
      float d=0.f,q=0.f;
      for (int i=0;i<32;i++){ int w=wsub+16*i; float m=M[(size_t)n*512+w]; float t2=m*q2[w]; d+=q1[w]*t2; q+=t2*t2; }
      for (int o=8;o;o>>=1){ d+=__shfl_down(d,o,16); q+=__shfl_down(q,o,16); }
      if (wsub==0){ float cs=d/(msc[32]*sqrtf(q)+1e-6f); mcr[r*32+n]=mh[r]*cs; } }
    __syncthreads();
  }
  if (tid<8){ int r=tid; float mx=-1e30f;
    for (int n=0;n<32;n++) mx=fmaxf(mx,mcr[r*32+n]);
    float sm=0.f;
    for (int n=0;n<32;n++){ float e=expf(mcr[r*32+n]-mx); mcr[r*32+n]=e; sm+=e; }
    float inv=1.f/sm;
    for (int n=0;n<32;n++) mcr[r*32+n]*=inv; }
  __syncthreads();
  // new read weights
  if (tid<256){ int r=tid>>5, n=tid&31;
    float v=mpi[r*3]*mbw[r*32+n]+mpi[r*3+1]*mcr[r*32+n]+mpi[r*3+2]*mfw[r*32+n];
    mwrn[tid]=v; wr_g[tid]=v; }
  __syncthreads();
  // reads = wr_new @ M_new  (cross-wg -> agent store)
  { int r=tid>>6, wsub=tid&63;
    for (int i2=0;i2<8;i2++){ int w=wsub+64*i2;
      float accv=0.f;
      for (int n=0;n<32;n++) accv+=mwrn[r*32+n]*M[(size_t)n*512+w];
      agst(&rout[r*512+w], accv); } }
  // state writeback (private -> plain)
  if (tid<32){ u_g[tid]=UU[tid]; ww_g[tid]=WWN[tid]; p_g[tid]=PP[tid]; }
  L_g[tid]=mL[tid]; L_g[tid+512]=mL[tid+512];
}

// ---------------------------------------------- persistent whole-recurrence
// Weights LDS-resident; cross-wg activations via agent atomics (no fences).
__global__ __launch_bounds__(TPB, 1)
void dnc_persist(
  const float* __restrict__ sent,
  const float* __restrict__ WAg, const float* __restrict__ b0,   // [1024][4608]
  const float* __restrict__ W1g, const float* __restrict__ b1,   // [1024][512]
  const float* __restrict__ W2g, const float* __restrict__ b2,   // [1024][512]
  const float* __restrict__ WXIg,const float* __restrict__ bxi,  // [10299][256]
  const float* __restrict__ WY,  const float* __restrict__ bout, // [140][4352]
  float* __restrict__ Hh, float* __restrict__ yh,
  float* __restrict__ reads2,
  float* __restrict__ h0g, float* __restrict__ h1g, float* __restrict__ h2g,
  float* __restrict__ c0g, float* __restrict__ c1g, float* __restrict__ c2g,
  float* __restrict__ z0g, float* __restrict__ z1g, float* __restrict__ z2g,
  float* __restrict__ xig,
  float* __restrict__ Mb, float* __restrict__ ug, float* __restrict__ wwg,
  float* __restrict__ pg, float* __restrict__ wrg, float* __restrict__ Lg,
  int* flags, int* genrep)
{
  extern __shared__ float lds[];
  float* sA   = lds;                 // 8 x 520
  float* sRed = lds + 4160;          // 64
  float* wA   = lds + 4224;          // 4 cols x 4608
  float* w1l  = lds + 22656;         // 4 cols x 512
  float* w2l  = lds + 24704;         // 4 cols x 512
  float* wxl  = lds + 26752;         // 48 cols x 256
  const int wg  = blockIdx.x;
  const int tid = threadIdx.x;
  const int cq = tid >> 7, kq = tid & 127;   // z-gemm layout (4 cols/wg)
  const int xc = tid >> 6, xk = tid & 63;    // xi layout (48 cols/wg)
  int seq = 0;

  // ---------------- one-time: weights -> LDS (plain, pre-launch data) ------
  for (int f=tid; f<18432; f+=TPB) wA[f]  = WAg[(size_t)wg*18432 + f];
  for (int f=tid; f<2048;  f+=TPB) w1l[f] = W1g[(size_t)wg*2048  + f];
  for (int f=tid; f<2048;  f+=TPB) w2l[f] = W2g[(size_t)wg*2048  + f];
  for (int f=tid; f<12288; f+=TPB){
    int cl = f>>8, k = f&255; int col = wg*48 + cl;
    wxl[f] = (col < 10299) ? WXIg[(size_t)col*256 + k] : 0.f;
  }
  const bool isy = (wg >= 8 && wg < 148);
  const float* wcolY = WY + (size_t)(isy ? (wg-8) : 0)*4352;
  __syncthreads();

  #pragma unroll 1
  for (int t=0; t<LSEQ; t++){
    const int rp = t&1, wp = rp^1, pprev = (t+1)&1;
    const float* readsPrev = reads2 + (size_t)pprev*32768;

    // ================= phase A: z0 gemm (K=4492 padded to 4608) =========
    {
      const float* h0p = h0g + pprev*2048;
      float acc[8] = {0,0,0,0,0,0,0,0};
      float av[8];
      #pragma unroll
      for (int s=0;s<8;s++){
        int kg = tid;
        av[s] = (kg<140) ? sent[((size_t)s*512 + t)*140 + kg]
                         : agld(&readsPrev[s*4096 + kg - 140]);
      }
      #pragma unroll 1
      for (int ch=0; ch<9; ch++){
        __syncthreads();
        #pragma unroll
        for (int s=0;s<8;s++) sA[s*520 + tid] = av[s];
        __syncthreads();
        if (ch < 8){
          int kg = (ch+1)*512 + tid;
          #pragma unroll
          for (int s=0;s<8;s++){
            float v;
            if (kg < 140)       v = sent[((size_t)s*512 + t)*140 + kg];
            else if (kg < 4236) v = agld(&readsPrev[s*4096 + kg - 140]);
            else if (kg < 4492) v = agld(&h0p[s*256 + (kg-4236)]);
            else                v = 0.f;
            av[s]=v;
          }
        }
        float4 wv = *reinterpret_cast<const float4*>(&wA[cq*4608 + ch*512 + (kq<<2)]);
        #pragma unroll
        for (int s=0;s<8;s++){
          float4 a = *reinterpret_cast<const float4*>(&sA[s*520 + (kq<<2)]);
          acc[s] += a.x*wv.x + a.y*wv.y + a.z*wv.z + a.w*wv.w;
        }
      }
      #pragma unroll
      for (int o=32;o;o>>=1)
        #pragma unroll
        for (int s=0;s<8;s++) acc[s]+=__shfl_down(acc[s],o,64);
      if ((tid&63)==0){ int wv2=tid>>6;
        #pragma unroll
        for (int s=0;s<8;s++) sRed[wv2*8+s]=acc[s]; }
      __syncthreads();
      if (tid<32){ int c=tid>>3, s=tid&7;
        agst(&z0g[s*1024 + wg*4 + c], sRed[c*16+s] + sRed[c*16+8+s] + b0[wg*4+c]); }
    }
    gbar(flags,genrep,++seq);

    // ================= phase B: cell0 + z1 gemm =========================
    {
      float4 w1v = *reinterpret_cast<const float4*>(&w1l[cq*512 + (kq<<2)]);
      if (tid<256){
        int j=tid;
        #pragma unroll
        for (int s=0;s<8;s++){
          float zi=agld(&z0g[s*1024+j]), zf=agld(&z0g[s*1024+256+j]);
          float zg=agld(&z0g[s*1024+512+j]), zo=agld(&z0g[s*1024+768+j]);
          float cold=agld(&c0g[rp*2048+s*256+j]);
          float cn=sigf(zf)*cold+sigf(zi)*tanhf(zg);
          float h=sigf(zo)*tanhf(cn);
          sA[s*520+j]=h;
          if (wg==8){ agst(&c0g[wp*2048+s*256+j],cn); agst(&h0g[rp*2048+s*256+j],h); }
        }
      } else {
        int j=tid-256;
        const float* h1p = h1g + pprev*2048;
        #pragma unroll
        for (int s=0;s<8;s++) sA[s*520+256+j]=agld(&h1p[s*256+j]);
      }
      __syncthreads();
      float acc[8]={0,0,0,0,0,0,0,0};
      #pragma unroll
      for (int s=0;s<8;s++){
        float4 a=*reinterpret_cast<const float4*>(&sA[s*520+(kq<<2)]);
        acc[s]+=a.x*w1v.x+a.y*w1v.y+a.z*w1v.z+a.w*w1v.w;
      }
      #pragma unroll
      for (int o=32;o;o>>=1)
        #pragma unroll
        for (int s=0;s<8;s++) acc[s]+=__shfl_down(acc[s],o,64);
      if ((tid&63)==0){ int wv2=tid>>6;
        #pragma unroll
        for (int s=0;s<8;s++) sRed[wv2*8+s]=acc[s]; }
      __syncthreads();
      if (tid<32){ int c=tid>>3, s=tid&7;
        agst(&z1g[s*1024 + wg*4 + c], sRed[c*16+s] + sRed[c*16+8+s] + b1[wg*4+c]); }
    }
    gbar(flags,genrep,++seq);

    // ================= phase C: cell1 + z2 gemm =========================
    {
      float4 w2v = *reinterpret_cast<const float4*>(&w2l[cq*512 + (kq<<2)]);
      if (tid<256){
        int j=tid;
        #pragma unroll
        for (int s=0;s<8;s++){
          float zi=agld(&z1g[s*1024+j]), zf=agld(&z1g[s*1024+256+j]);
          float zg=agld(&z1g[s*1024+512+j]), zo=agld(&z1g[s*1024+768+j]);
          float cold=agld(&c1g[rp*2048+s*256+j]);
          float cn=sigf(zf)*cold+sigf(zi)*tanhf(zg);
          float h=sigf(zo)*tanhf(cn);
          sA[s*520+j]=h;
          if (wg==8){ agst(&c1g[wp*2048+s*256+j],cn); agst(&h1g[rp*2048+s*256+j],h); }
        }
      } else {
        int j=tid-256;
        const float* h2p = h2g + pprev*2048;
        #pragma unroll
        for (int s=0;s<8;s++) sA[s*520+256+j]=agld(&h2p[s*256+j]);
      }
      __syncthreads();
      float acc[8]={0,0,0,0,0,0,0,0};
      #pragma unroll
      for (int s=0;s<8;s++){
        float4 a=*reinterpret_cast<const float4*>(&sA[s*520+(kq<<2)]);
        acc[s]+=a.x*w2v.x+a.y*w2v.y+a.z*w2v.z+a.w*w2v.w;
      }
      #pragma unroll
      for (int o=32;o;o>>=1)
        #pragma unroll
        for (int s=0;s<8;s++) acc[s]+=__shfl_down(acc[s],o,64);
      if ((tid&63)==0){ int wv2=tid>>6;
        #pragma unroll
        for (int s=0;s<8;s++) sRed[wv2*8+s]=acc[s]; }
      __syncthreads();
      if (tid<32){ int c=tid>>3, s=tid&7;
        agst(&z2g[s*1024 + wg*4 + c], sRed[c*16+s] + sRed[c*16+8+s] + b2[wg*4+c]); }
    }
    gbar(flags,genrep,++seq);

    // ================= phase D: cell2 + xi gemm =========================
    {
      if (tid<256){
        int j=tid;
        #pragma unroll
        for (int s=0;s<8;s++){
          float zi=agld(&z2g[s*1024+j]), zf=agld(&z2g[s*1024+256+j]);
          float zg=agld(&z2g[s*1024+512+j]), zo=agld(&z2g[s*1024+768+j]);
          float cold=agld(&c2g[rp*2048+s*256+j]);
          float cn=sigf(zf)*cold+sigf(zi)*tanhf(zg);
          float h2=sigf(zo)*tanhf(cn);
          float hc=fminf(fmaxf(h2,-20.f),20.f);
          sA[s*520+j]=hc;
          if (wg==8){ agst(&c2g[wp*2048+s*256+j],cn); agst(&h2g[rp*2048+s*256+j],h2);
                      agst(&Hh[((size_t)t*8+s)*256+j],hc); }
        }
      }
      __syncthreads();
      float accx[6][8];
      #pragma unroll
      for (int cc=0;cc<6;cc++)
        #pragma unroll
        for (int s=0;s<8;s++) accx[cc][s]=0.f;
      #pragma unroll
      for (int s=0;s<8;s++){
        float4 a = *reinterpret_cast<const float4*>(&sA[s*520 + (xk<<2)]);
        #pragma unroll
        for (int cc=0;cc<6;cc++){
          float4 wv = *reinterpret_cast<const float4*>(&wxl[(xc*6+cc)*256 + (xk<<2)]);
          accx[cc][s] += a.x*wv.x + a.y*wv.y + a.z*wv.z + a.w*wv.w;
        }
      }
      #pragma unroll
      for (int o=32;o;o>>=1)
        #pragma unroll
        for (int cc=0;cc<6;cc++)
          #pragma unroll
          for (int s=0;s<8;s++) accx[cc][s]+=__shfl_down(accx[cc][s],o,64);
      if ((tid&63)==0){
        #pragma unroll
        for (int cc=0;cc<6;cc++){
          int col = wg*48 + xc*6 + cc;
          if (col < 10299){
            #pragma unroll
            for (int s=0;s<8;s++) agst(&xig[(size_t)s*10299+col], accx[cc][s]+bxi[col]);
          }
        }
      }
    }
    gbar(flags,genrep,++seq);

    // ================= phase E: memory update (wg<8) + y(t-1) ==========
    if (wg < 8){
      mem_phase(lds, xig + (size_t)wg*10299, Mb + (size_t)wg*16384,
                ug+wg*32, wwg+wg*32, pg+wg*32, wrg+wg*256, Lg+wg*1024,
                reads2 + (size_t)rp*32768 + wg*4096);
    } else if (isy && t > 0){
      int ty = t-1;
      const float* rdp = reads2 + (size_t)(ty&1)*32768;
      float wy[9];
      #pragma unroll
      for (int ch=0;ch<9;ch++){ int k=ch*512+tid; wy[ch]=(k<4352)? wcolY[k] : 0.f; }
      float acy[8]={0,0,0,0,0,0,0,0};
      #pragma unroll
      for (int ch=0;ch<9;ch++){
        int kg=ch*512+tid;
        #pragma unroll
        for (int s=0;s<8;s++){
          float a;
          if (kg<256)       a=agld(&Hh[((size_t)ty*8+s)*256+kg]);
          else if (kg<4352) a=agld(&rdp[s*4096+kg-256]);
          else              a=0.f;
          acy[s]+=a*wy[ch];
        }
      }
      #pragma unroll
      for (int o=32;o;o>>=1)
        #pragma unroll
        for (int s=0;s<8;s++) acy[s]+=__shfl_down(acy[s],o,64);
      if ((tid&63)==0){ int wv2=tid>>6;
        #pragma unroll
        for (int s=0;s<8;s++) sRed[wv2*8+s]=acy[s]; }
      __syncthreads();
      if (tid<8){ float v=0.f;
        #pragma unroll
        for (int w=0;w<8;w++) v+=sRed[w*8+tid];
        yh[((size_t)tid*512+ty)*140+(wg-8)]=v+bout[wg-8]; }
    }
    gbar(flags,genrep,++seq);
  }

  // ---------------- final y(511) ----------------
  if (isy){
    int ty = 511;
    const float* rdp = reads2 + (size_t)(ty&1)*32768;
    float wy[9];
    #pragma unroll
    for (int ch=0;ch<9;ch++){ int k=ch*512+tid; wy[ch]=(k<4352)? wcolY[k] : 0.f; }
    float acy[8]={0,0,0,0,0,0,0,0};
    #pragma unroll
    for (int ch=0;ch<9;ch++){
      int kg=ch*512+tid;
      #pragma unroll
      for (int s=0;s<8;s++){
        float a;
        if (kg<256)       a=agld(&Hh[((size_t)ty*8+s)*256+kg]);
        else if (kg<4352) a=agld(&rdp[s*4096+kg-256]);
        else              a=0.f;
        acy[s]+=a*wy[ch];
      }
    }
    #pragma unroll
    for (int o=32;o;o>>=1)
      #pragma unroll
      for (int s=0;s<8;s++) acy[s]+=__shfl_down(acy[s],o,64);
    if ((tid&63)==0){ int wv2=tid>>6;
      #pragma unroll
      for (int s=0;s<8;s++) sRed[wv2*8+s]=acy[s]; }
    __syncthreads();
    if (tid<8){ float v=0.f;
      #pragma unroll
      for (int w=0;w<8;w++) v+=sRed[w*8+tid];
      yh[((size_t)tid*512+ty)*140+(wg-8)]=v+bout[wg-8]; }
  }
}

// ---------------------------------------- generic 16-row tiled gemm (lda==K)
__global__ __launch_bounds__(256)
void gemm16(int M, int N, int K,
            const float* __restrict__ A, long long sAb, int lda,
            const float* __restrict__ Bm, long long sBb, int ldb,
            float* __restrict__ C, long long sCb, int ldc,
            const float* __restrict__ bias, int relu)
{
  __shared__ float sAh[16*512];
  const int tid = threadIdx.x;
  const float* Ab = A + (size_t)blockIdx.y*sAb;
  const float* Bb = Bm + (size_t)blockIdx.y*sBb;
  float* Cb = C + (size_t)blockIdx.y*sCb;
  const int m0 = blockIdx.x*16;
  const int tot = 16*K;
  for (int f = tid; f < tot; f += 256) sAh[f] = Ab[(size_t)m0*lda + f]; // lda==K
  __syncthreads();
  int c = (tid & 63)*4; int rg = tid >> 6;
  if (c >= N) return;
  float acc[4][4] = {};
  for (int k=0;k<K;k++){
    float4 bv = *reinterpret_cast<const float4*>(Bb + (size_t)k*ldb + c);
    #pragma unroll
    for (int rr=0;rr<4;rr++){
      float a = sAh[(rg*4+rr)*K + k];
      acc[rr][0] += a*bv.x; acc[rr][1] += a*bv.y; acc[rr][2] += a*bv.z; acc[rr][3] += a*bv.w;
    }
  }
  for (int rr=0;rr<4;rr++){
    int m = m0 + rg*4 + rr;
    #pragma unroll
    for (int e=0;e<4;e++){
      float v = acc[rr][e] + (bias ? bias[c+e] : 0.f);
      if (relu) v = fmaxf(v, 0.f);
      Cb[(size_t)m*ldc + c + e] = v;
    }
  }
}

// ------------------------------------------------------------ bilinear head
__global__ __launch_bounds__(256)
void bilin(const float* __restrict__ s0, const float* __restrict__ t0,
           const float* __restrict__ dis_emb, const int* __restrict__ dht,
           const int* __restrict__ dth, const float* __restrict__ Wb,
           const float* __restrict__ bb, float* __restrict__ out)
{
  __shared__ float sS[BI][33];
  __shared__ float sT[32][152];
  const int tid = threadIdx.x;
  const int bp0 = blockIdx.x*32;
  for (int f = tid; f < 32*BI; f += 256){
    int pp = f / BI, i = f % BI;
    int bp = bp0 + pp;
    float sv, tv;
    if (i < 128){ sv = s0[(size_t)bp*128 + i]; tv = t0[(size_t)bp*128 + i]; }
    else {
      sv = dis_emb[(size_t)dht[bp]*20 + (i-128)];
      tv = dis_emb[(size_t)dth[bp]*20 + (i-128)];
    }
    sS[i][pp] = sv; sT[pp][i] = tv;
  }
  __syncthreads();
  const int ppg = tid >> 5, jb = tid & 31;
  const int pp0 = ppg*4;
  const int k0 = blockIdx.y*49, kend = min(k0+49, RELK);
  for (int k = k0; k < kend; k++){
    const float* Wk = Wb + (size_t)k*BI*BI;
    float acc[4][5];
    #pragma unroll
    for (int a=0;a<4;a++) for (int b=0;b<5;b++) acc[a][b]=0.f;
    for (int i=0;i<BI;i++){
      float sv0 = sS[i][pp0], sv1 = sS[i][pp0+1], sv2 = sS[i][pp0+2], sv3 = sS[i][pp0+3];
      const float* wrow = Wk + i*BI;
      #pragma unroll
      for (int jj=0;jj<5;jj++){
        int j = jb + 32*jj;
        if (j < BI){
          float w = wrow[j];
          acc[0][jj] += sv0*w; acc[1][jj] += sv1*w; acc[2][jj] += sv2*w; acc[3][jj] += sv3*w;
        }
      }
    }
    float dot[4] = {0.f,0.f,0.f,0.f};
    #pragma unroll
    for (int jj=0;jj<5;jj++){
      int j = jb + 32*jj;
      if (j < BI){
        #pragma unroll
        for (int p4=0;p4<4;p4++) dot[p4] += acc[p4][jj]*sT[pp0+p4][j];
      }
    }
    #pragma unroll
    for (int p4=0;p4<4;p4++)
      for (int o=16;o;o>>=1) dot[p4] += __shfl_down(dot[p4], o, 32);
    if (jb == 0){
      #pragma unroll
      for (int p4=0;p4<4;p4++)
        out[(size_t)(bp0+pp0+p4)*RELK + k] = dot[p4] + bb[k];
    }
  }
}

// =========================================================== host launcher
extern "C" void kernel_launch(void* const* d_in, const int* in_sizes, int n_in,
                              void* d_out, int out_size, void* d_ws, size_t ws_size,
                              hipStream_t stream)
{
  (void)in_sizes; (void)n_in; (void)out_size; (void)ws_size;
  const int*   ctx_idx = (const int*)  d_in[0];
  const int*   pos     = (const int*)  d_in[1];
  const int*   nerI    = (const int*)  d_in[2];
  const float* h_map   = (const float*)d_in[5];
  const float* t_map   = (const float*)d_in[6];
  const int*   dht     = (const int*)  d_in[8];
  const int*   dth     = (const int*)  d_in[9];
  const float* wemb    = (const float*)d_in[10];
  const float* eemb    = (const float*)d_in[11];
  const float* nemb    = (const float*)d_in[12];
  const float* demb    = (const float*)d_in[13];
  const float* Wih0    = (const float*)d_in[14];
  const float* Whh0    = (const float*)d_in[15];
  const float* b0      = (const float*)d_in[16];
  const float* Wih1    = (const float*)d_in[17];
  const float* Whh1    = (const float*)d_in[18];
  const float* b1      = (const float*)d_in[19];
  const float* Wih2    = (const float*)d_in[20];
  const float* Whh2    = (const float*)d_in[21];
  const float* b2      = (const float*)d_in[22];
  const float* Wxi     = (const float*)d_in[23];
  const float* bxi     = (const float*)d_in[24];
  const float* Wout    = (const float*)d_in[25];
  const float* bout    = (const float*)d_in[26];
  const float* Wfin    = (const float*)d_in[27];
  const float* bfin    = (const float*)d_in[28];
  const float* Wre     = (const float*)d_in[29];
  const float* bre     = (const float*)d_in[30];
  const float* Wbili   = (const float*)d_in[31];
  const float* bbili   = (const float*)d_in[32];

  float* ws    = (float*)d_ws;
  float* sent  = ws;                    // [8][512][140]   573440
  float* Hh    = sent + 573440;         // [512][8][256]  1048576
  float* yh    = Hh + 1048576;          // [8][512][140]   573440
  float* s0b   = yh + 573440;           // [4096][128]     524288
  float* t0b   = s0b + 524288;          // [4096][128]     524288
  float* reads2= t0b + 524288;          // [2][8][4096]     65536
  float* h0g   = reads2 + 65536;        // [2][8][256]       4096
  float* h1g   = h0g + 4096;
  float* h2g   = h1g + 4096;
  float* c0g   = h2g + 4096;
  float* c1g   = c0g + 4096;
  float* c2g   = c1g + 4096;
  float* z0g   = c2g + 4096;            // [8][1024]         8192
  float* z1g   = z0g + 8192;
  float* z2g   = z1g + 8192;
  float* xig   = z2g + 8192;            // [8][10299]       82392
  float* Mb    = xig + 82392;           // [8][32][512]    131072
  float* ug    = Mb + 131072;           // [8][32]
  float* wwg   = ug + 256;
  float* pg    = wwg + 256;
  float* wrg   = pg + 256;              // [8][8][32]
  float* Lg    = wrg + 2048;            // [8][32][32]
  float* barf  = Lg + 8192;             // flags 256*16 + genrep 32*16 = 4608 ints
  float* WA_T  = barf + 4608;           // [1024][4608]   4718592
  float* W1T   = WA_T + 4718592;        // [1024][512]     524288
  float* W2T   = W1T + 524288;          // [1024][512]     524288
  float* WXIT  = W2T + 524288;          // [10299][256]   2636544
  float* WYT   = WXIT + 2636544;        // [140][4352]     609280
  float* o256  = Hh;                    // alias: Hh dead after persist+gemm use
  float* ctxb  = sent;                  // alias: sent dead after persist
  int* flags  = (int*)barf;
  int* genrep = flags + 256*FSTR;

  size_t stateFloats = (size_t)(WA_T - reads2);
  hipMemsetAsync(reads2, 0, stateFloats*sizeof(float), stream);

  // one-time transposed/concatenated weight copies
  hipLaunchKernelGGL(k_tr, dim3(18432), dim3(256), 0, stream,
                     Wih0, Whh0, 1024, 4236, 256, 4608, (long long)4718592, WA_T);
  hipLaunchKernelGGL(k_tr, dim3(2048), dim3(256), 0, stream,
                     Wih1, Whh1, 1024, 256, 256, 512, (long long)524288, W1T);
  hipLaunchKernelGGL(k_tr, dim3(2048), dim3(256), 0, stream,
                     Wih2, Whh2, 1024, 256, 256, 512, (long long)524288, W2T);
  hipLaunchKernelGGL(k_tr, dim3(10299), dim3(256), 0, stream,
                     Wxi, Wxi, 10299, 256, 0, 256, (long long)2636544, WXIT);
  hipLaunchKernelGGL(k_tr, dim3(2380), dim3(256), 0, stream,
                     Wout, Wout, 140, 4352, 0, 4352, (long long)609280, WYT);

  hipLaunchKernelGGL(k_sent, dim3((573440+255)/256), dim3(256), 0, stream,
                     ctx_idx, pos, nerI, wemb, eemb, nemb, sent);

  // allow >64KB dynamic LDS (host-side attribute set; not a stream op)
  hipFuncSetAttribute(reinterpret_cast<const void*>(dnc_persist),
                      hipFuncAttributeMaxDynamicSharedMemorySize, LDSB);

  hipLaunchKernelGGL(dnc_persist, dim3(NWG), dim3(TPB), LDSB, stream,
                     sent, WA_T, b0, W1T, b1, W2T, b2, WXIT, bxi, WYT, bout,
                     Hh, yh, reads2,
                     h0g, h1g, h2g, c0g, c1g, c2g, z0g, z1g, z2g, xig,
                     Mb, ug, wwg, pg, wrg, Lg, flags, genrep);

  // out = ys @ W_final + b_final          [4096,140]x[140,256]
  hipLaunchKernelGGL(gemm16, dim3(256,1), dim3(256), 0, stream,
                     4096, 256, 140, yh, (long long)0, 140, Wfin, (long long)0, 256,
                     o256, (long long)0, 256, bfin, 0);
  // ctx = relu(out @ W_re + b_re)         [4096,256]x[256,128]
  hipLaunchKernelGGL(gemm16, dim3(256,1), dim3(256), 0, stream,
                     4096, 128, 256, o256, (long long)0, 256, Wre, (long long)0, 128,
                     ctxb, (long long)0, 128, bre, 1);
  // s0 / t0 : per-batch [512,512]x[512,128]
  hipLaunchKernelGGL(gemm16, dim3(32,8), dim3(256), 0, stream,
                     512, 128, 512, h_map, (long long)(512*512), 512,
                     ctxb, (long long)(512*128), 128,
                     s0b, (long long)(512*128), 128, (const float*)nullptr, 0);
  hipLaunchKernelGGL(gemm16, dim3(32,8), dim3(256), 0, stream,
                     512, 128, 512, t_map, (long long)(512*512), 512,
                     ctxb, (long long)(512*128), 128,
                     t0b, (long long)(512*128), 128, (const float*)nullptr, 0);
  // bilinear head
  hipLaunchKernelGGL(bilin, dim3(128,2), dim3(256), 0, stream,
                     s0b, t0b, demb, dht, dth, Wbili, bbili, (float*)d_out);
}